// Round 5
// baseline (3470.207 us; speedup 1.0000x reference)
//
#include <hip/hip_runtime.h>
#include <math.h>

// Problem constants
#define BB   32
#define CIN  16
#define C1   72      // (16+2)*2*2
#define NTOK 1024    // 32*32
#define HH   64
#define WW2  64

// ---------------------------------------------------------------------------
// Kernel 1: coord-concat + pixel_unshuffle -> t [B,72,1024]; per-token
// channel-norm -> tn. One thread per (b, token). 128-thr blocks so all CUs
// get work (was 128 blocks of 256 -> half the CUs idle).
// ---------------------------------------------------------------------------
__global__ __launch_bounds__(128) void k1_build(const float* __restrict__ x,
                                                float* __restrict__ t,
                                                float* __restrict__ tn) {
  int gid = blockIdx.x * 128 + threadIdx.x;   // 32768 threads
  int b = gid >> 10;
  int n = gid & 1023;
  int hh = n >> 5, ww = n & 31;
  float vals[C1];
  float ss = 0.f;
#pragma unroll
  for (int c1 = 0; c1 < C1; ++c1) {
    int c = c1 >> 2, sh = (c1 >> 1) & 1, sw = c1 & 1;
    int h = 2 * hh + sh, w = 2 * ww + sw;
    float val;
    if (c < CIN) {
      val = x[((b * CIN + c) * HH + h) * WW2 + w];
    } else {
      float r = fmaxf(sqrtf((float)(h * h + w * w)), 1e-12f);
      val = (c == CIN ? (float)h : (float)w) / r;
    }
    vals[c1] = val;
    ss += val * val;
  }
  float inv = 1.0f / fmaxf(sqrtf(ss), 1e-12f);
#pragma unroll
  for (int c1 = 0; c1 < C1; ++c1) {
    int o = (b * C1 + c1) * NTOK + n;
    t[o]  = vals[c1];
    tn[o] = vals[c1] * inv;
  }
}

// ---------------------------------------------------------------------------
// Kernel 2 (v2): V = t @ Wv^T + bv. 64x64 NT-GEMM, XCD-swizzled grid (kept).
// NEW: BK=32 (barriers 128 -> 32), double-buffered LDS, register prefetch of
// the next K-tile issued BEFORE the compute phase (T14): global latency
// hides under 512 FMAs. One barrier per K-step.
// Read-bank analysis ([64][36] rows): a-reads 4 addrs broadcast; b-reads
// 16 addrs, 2 words/bank = free.
// ---------------------------------------------------------------------------
#define K2_BK 32
#define K2_LD 36
__global__ __launch_bounds__(256, 4) void k2_vproj(const float* __restrict__ A,
                                                   const float* __restrict__ Wv,
                                                   const float* __restrict__ bv,
                                                   float* __restrict__ V) {
  __shared__ float As[2][64][K2_LD];
  __shared__ float Bs[2][64][K2_LD];
  int wg = blockIdx.x;                  // 0..575
  int xcd = wg & 7;
  int q = wg >> 3;                      // 0..71
  int row0 = (q >> 1) * 64;             // 36 row tiles
  int col0 = (xcd * 2 + (q & 1)) * 64;  // 16 col tiles, 2 per XCD
  int tid = threadIdx.x;
  int tx = tid & 15, ty = tid >> 4;
  int r0 = tid >> 3;                    // 0..31 (loads rows r0, r0+32)
  int ch = tid & 7;                     // k-chunk 0..7 (16B each)
  const float* Ap = A  + (row0 + r0) * 1024 + ch * 4;
  const float* Bp = Wv + (col0 + r0) * 1024 + ch * 4;

  // prologue: stage K-step 0
  float4 a0 = *(const float4*)Ap;
  float4 a1 = *(const float4*)(Ap + 32 * 1024);
  float4 b0 = *(const float4*)Bp;
  float4 b1 = *(const float4*)(Bp + 32 * 1024);
  *(float4*)&As[0][r0][ch * 4]      = a0;
  *(float4*)&As[0][r0 + 32][ch * 4] = a1;
  *(float4*)&Bs[0][r0][ch * 4]      = b0;
  *(float4*)&Bs[0][r0 + 32][ch * 4] = b1;

  float acc[4][4];
#pragma unroll
  for (int i = 0; i < 4; ++i)
#pragma unroll
    for (int j = 0; j < 4; ++j) acc[i][j] = 0.f;
  __syncthreads();

#pragma unroll 2
  for (int s = 0; s < 32; ++s) {
    int cur = s & 1;
    if (s < 31) {                       // issue next K-tile loads (no use yet)
      int off = (s + 1) * K2_BK;
      a0 = *(const float4*)(Ap + off);
      a1 = *(const float4*)(Ap + off + 32 * 1024);
      b0 = *(const float4*)(Bp + off);
      b1 = *(const float4*)(Bp + off + 32 * 1024);
    }
#pragma unroll
    for (int kq = 0; kq < K2_BK; kq += 4) {
      float4 av[4], bvv[4];
#pragma unroll
      for (int i = 0; i < 4; ++i) av[i] = *(const float4*)&As[cur][ty * 4 + i][kq];
#pragma unroll
      for (int j = 0; j < 4; ++j) bvv[j] = *(const float4*)&Bs[cur][tx + 16 * j][kq];
#pragma unroll
      for (int i = 0; i < 4; ++i)
#pragma unroll
        for (int j = 0; j < 4; ++j)
          acc[i][j] += av[i].x * bvv[j].x + av[i].y * bvv[j].y +
                       av[i].z * bvv[j].z + av[i].w * bvv[j].w;
    }
    if (s < 31) {                       // write prefetched tile (vmcnt waits here,
      int nxt = cur ^ 1;                //  latency already covered by compute)
      *(float4*)&As[nxt][r0][ch * 4]      = a0;
      *(float4*)&As[nxt][r0 + 32][ch * 4] = a1;
      *(float4*)&Bs[nxt][r0][ch * 4]      = b0;
      *(float4*)&Bs[nxt][r0 + 32][ch * 4] = b1;
    }
    __syncthreads();
  }
#pragma unroll
  for (int i = 0; i < 4; ++i) {
    int r = row0 + ty * 4 + i;
#pragma unroll
    for (int j = 0; j < 4; ++j) {
      int cidx = col0 + tx + 16 * j;
      V[r * 1024 + cidx] = acc[i][j] + bv[cidx];
    }
  }
}

// ---------------------------------------------------------------------------
// Kernel 3 (v4): cosine-sim + online top-3 + softmax.
// v3 structure kept (512 thr = 16 ty x 32 tx, 4x4 per thread, 64 rows x
// 8 x 128-col tiles, skip-max guard, XCD swizzle).
// NEW: register prefetch of next btile (5 float4/thread) issued BEFORE the
// tile's compute phase, written to LDS after the consume-barrier (T14) ->
// removes the exposed global latency between the two per-tile barriers.
// ---------------------------------------------------------------------------
#define INS(TV, TI, d, di)                                              \
  {                                                                     \
    if ((d) > TV[0] || ((d) == TV[0] && (di) < TI[0])) {                \
      TV[2] = TV[1]; TI[2] = TI[1];                                     \
      TV[1] = TV[0]; TI[1] = TI[0];                                     \
      TV[0] = (d);   TI[0] = (di);                                      \
    } else if ((d) > TV[1] || ((d) == TV[1] && (di) < TI[1])) {         \
      TV[2] = TV[1]; TI[2] = TI[1];                                     \
      TV[1] = (d);   TI[1] = (di);                                      \
    } else if ((d) > TV[2] || ((d) == TV[2] && (di) < TI[2])) {         \
      TV[2] = (d);   TI[2] = (di);                                      \
    }                                                                   \
  }

__global__ __launch_bounds__(512, 4) void k3_topk(const float* __restrict__ tn,
                                                  int* __restrict__ idxo,
                                                  float* __restrict__ attno) {
  __shared__ float smem[C1 * 64 + C1 * 128];   // arow | btile, 55.3 KB
  float* arow  = smem;              // [C1][64]
  float* btile = smem + C1 * 64;    // [C1][128]

  int wg = blockIdx.x;              // 0..511
  int xcd = wg & 7;
  int q = wg >> 3;                  // 0..63
  int b  = xcd * 4 + (q >> 4);      // 4 batches per XCD
  int n0 = (q & 15) * 64;
  int tid = threadIdx.x;
  int tx = tid & 31;   // col group: cols tx*4..+3 (of 128)
  int ty = tid >> 5;   // row group: rows ty*4..+3 (of 64)

  const float* gbase = tn + b * C1 * NTOK;

  // per-thread staging slots for btile: 2304 float4 / 512 thr = 4.5
  int t0 = tid, t1 = tid + 512, t2 = tid + 1024, t3 = tid + 1536, t4 = tid + 2048;
  int go0 = (t0 >> 5) * NTOK + (t0 & 31) * 4, lo0 = (t0 >> 5) * 128 + (t0 & 31) * 4;
  int go1 = (t1 >> 5) * NTOK + (t1 & 31) * 4, lo1 = (t1 >> 5) * 128 + (t1 & 31) * 4;
  int go2 = (t2 >> 5) * NTOK + (t2 & 31) * 4, lo2 = (t2 >> 5) * 128 + (t2 & 31) * 4;
  int go3 = (t3 >> 5) * NTOK + (t3 & 31) * 4, lo3 = (t3 >> 5) * 128 + (t3 & 31) * 4;
  int go4 = (t4 >> 5) * NTOK + (t4 & 31) * 4, lo4 = (t4 >> 5) * 128 + (t4 & 31) * 4;
  bool has4 = (t4 < C1 * 32);       // tid < 256

  // stage this block's 64 rows (72 channels)
  for (int e4 = tid; e4 < C1 * 16; e4 += 512) {
    int c = e4 >> 4, qq = e4 & 15;
    *(float4*)&arow[c * 64 + qq * 4] =
        *(const float4*)&tn[(b * C1 + c) * NTOK + n0 + qq * 4];
  }
  // stage btile tile 0 directly
  {
    *(float4*)&btile[lo0] = *(const float4*)&gbase[go0];
    *(float4*)&btile[lo1] = *(const float4*)&gbase[go1];
    *(float4*)&btile[lo2] = *(const float4*)&gbase[go2];
    *(float4*)&btile[lo3] = *(const float4*)&gbase[go3];
    if (has4) *(float4*)&btile[lo4] = *(const float4*)&gbase[go4];
  }

  float tv[4][3];
  int   ti[4][3];
#pragma unroll
  for (int ri = 0; ri < 4; ++ri) {
    tv[ri][0] = tv[ri][1] = tv[ri][2] = -INFINITY;
    ti[ri][0] = ti[ri][1] = ti[ri][2] = 0x7fffffff;
  }
  __syncthreads();

#pragma unroll 1
  for (int tl = 0; tl < 8; ++tl) {
    // issue next-tile loads (values not used until after the barrier)
    float4 p0, p1, p2, p3, p4;
    if (tl < 7) {
      const float* gb = gbase + (tl + 1) * 128;
      p0 = *(const float4*)&gb[go0];
      p1 = *(const float4*)&gb[go1];
      p2 = *(const float4*)&gb[go2];
      p3 = *(const float4*)&gb[go3];
      if (has4) p4 = *(const float4*)&gb[go4];
    }

    int m0 = tl * 128;
    float4 acc0 = {0,0,0,0}, acc1 = {0,0,0,0}, acc2 = {0,0,0,0}, acc3 = {0,0,0,0};
#pragma unroll 4
    for (int c = 0; c < C1; ++c) {
      float4 av  = *(const float4*)&arow[c * 64 + ty * 4];
      float4 bv4 = *(const float4*)&btile[c * 128 + tx * 4];
      acc0.x += av.x * bv4.x; acc0.y += av.x * bv4.y;
      acc0.z += av.x * bv4.z; acc0.w += av.x * bv4.w;
      acc1.x += av.y * bv4.x; acc1.y += av.y * bv4.y;
      acc1.z += av.y * bv4.z; acc1.w += av.y * bv4.w;
      acc2.x += av.z * bv4.x; acc2.y += av.z * bv4.y;
      acc2.z += av.z * bv4.z; acc2.w += av.z * bv4.w;
      acc3.x += av.w * bv4.x; acc3.y += av.w * bv4.y;
      acc3.z += av.w * bv4.z; acc3.w += av.w * bv4.w;
    }
    int cb = m0 + tx * 4;
    float mx;
    mx = fmaxf(fmaxf(acc0.x, acc0.y), fmaxf(acc0.z, acc0.w));
    if (mx > tv[0][2]) {
      INS(tv[0], ti[0], acc0.x, cb + 0); INS(tv[0], ti[0], acc0.y, cb + 1);
      INS(tv[0], ti[0], acc0.z, cb + 2); INS(tv[0], ti[0], acc0.w, cb + 3);
    }
    mx = fmaxf(fmaxf(acc1.x, acc1.y), fmaxf(acc1.z, acc1.w));
    if (mx > tv[1][2]) {
      INS(tv[1], ti[1], acc1.x, cb + 0); INS(tv[1], ti[1], acc1.y, cb + 1);
      INS(tv[1], ti[1], acc1.z, cb + 2); INS(tv[1], ti[1], acc1.w, cb + 3);
    }
    mx = fmaxf(fmaxf(acc2.x, acc2.y), fmaxf(acc2.z, acc2.w));
    if (mx > tv[2][2]) {
      INS(tv[2], ti[2], acc2.x, cb + 0); INS(tv[2], ti[2], acc2.y, cb + 1);
      INS(tv[2], ti[2], acc2.z, cb + 2); INS(tv[2], ti[2], acc2.w, cb + 3);
    }
    mx = fmaxf(fmaxf(acc3.x, acc3.y), fmaxf(acc3.z, acc3.w));
    if (mx > tv[3][2]) {
      INS(tv[3], ti[3], acc3.x, cb + 0); INS(tv[3], ti[3], acc3.y, cb + 1);
      INS(tv[3], ti[3], acc3.z, cb + 2); INS(tv[3], ti[3], acc3.w, cb + 3);
    }

    __syncthreads();               // all btile reads done
    if (tl < 7) {
      *(float4*)&btile[lo0] = p0;
      *(float4*)&btile[lo1] = p1;
      *(float4*)&btile[lo2] = p2;
      *(float4*)&btile[lo3] = p3;
      if (has4) *(float4*)&btile[lo4] = p4;
    }
    __syncthreads();               // new tile visible
  }

  // merge 32 col-groups x 3 per row; reuse smem (staging done)
  float* mv = smem;                  // 64*32*3 = 6144 floats
  int*   mi = (int*)(smem + 6144);   // 6144 ints (12288 <= 13824)
#pragma unroll
  for (int ri = 0; ri < 4; ++ri) {
    int row = ty * 4 + ri;
#pragma unroll
    for (int j = 0; j < 3; ++j) {
      mv[(row * 32 + tx) * 3 + j] = tv[ri][j];
      mi[(row * 32 + tx) * 3 + j] = ti[ri][j];
    }
  }
  __syncthreads();
  if (tid < 64) {
    float fv[3] = {-INFINITY, -INFINITY, -INFINITY};
    int   fi[3] = {0x7fffffff, 0x7fffffff, 0x7fffffff};
    for (int g = 0; g < 32; ++g) {
#pragma unroll
      for (int j = 0; j < 3; ++j) {
        float d  = mv[(tid * 32 + g) * 3 + j];
        int   di = mi[(tid * 32 + g) * 3 + j];
        INS(fv, fi, d, di);
      }
    }
    float e1 = expf(fv[1] - fv[0]), e2 = expf(fv[2] - fv[0]);
    float inv = 1.0f / (1.0f + e1 + e2);
    int ob = (b * NTOK + n0 + tid) * 3;
    idxo[ob] = fi[0]; idxo[ob + 1] = fi[1]; idxo[ob + 2] = fi[2];
    attno[ob] = inv; attno[ob + 1] = e1 * inv; attno[ob + 2] = e2 * inv;
  }
}

// ---------------------------------------------------------------------------
// Kernel 4: gather top-3 neighbor value columns (x attn) into LDS, then
// conv1d(kernel=K,stride=K) == [72 x 216] GEMM per token. (unchanged)
// ---------------------------------------------------------------------------
__global__ __launch_bounds__(256) void k4_conv1d(const float* __restrict__ v,
                                                 const int* __restrict__ idx,
                                                 const float* __restrict__ attn,
                                                 const float* __restrict__ conv_w,
                                                 const float* __restrict__ conv_b,
                                                 float* __restrict__ out1d) {
  __shared__ float prime[64][220];
  __shared__ int   sidx[64][3];
  __shared__ float satt[64][3];
  int wg = blockIdx.x;              // 0..511
  int xcd = wg & 7;
  int q = wg >> 3;                  // 0..63
  int b  = xcd * 4 + (q >> 4);
  int n0 = (q & 15) * 64;
  int tid = threadIdx.x;
  if (tid < 192) {
    int tok = tid / 3, k = tid % 3;
    sidx[tok][k] = idx[(b * NTOK + n0 + tok) * 3 + k];
    satt[tok][k] = attn[(b * NTOK + n0 + tok) * 3 + k];
  }
  __syncthreads();
  for (int e = tid; e < 64 * 216; e += 256) {
    int tok = e & 63, ck = e >> 6;
    int c = ck / 3, k = ck - c * 3;
    prime[tok][ck] = v[(b * C1 + c) * NTOK + sidx[tok][k]] * satt[tok][k];
  }
  __syncthreads();
  int tok = tid & 63;
  int obase = __builtin_amdgcn_readfirstlane((int)(tid >> 6)) * 18;
  float acc[18];
#pragma unroll
  for (int j = 0; j < 18; ++j) acc[j] = 0.f;
  for (int ck4 = 0; ck4 < 54; ++ck4) {
    float4 p4 = *(const float4*)&prime[tok][ck4 * 4];
#pragma unroll
    for (int j = 0; j < 18; ++j) {
      float4 w4 = *(const float4*)&conv_w[(obase + j) * 216 + ck4 * 4];
      acc[j] += p4.x * w4.x + p4.y * w4.y + p4.z * w4.z + p4.w * w4.w;
    }
  }
#pragma unroll
  for (int j = 0; j < 18; ++j) {
    int o = obase + j;
    out1d[(b * C1 + o) * NTOK + n0 + tok] = acc[j] + conv_b[o];
  }
}

// ---------------------------------------------------------------------------
// Kernel 5: pixel_shuffle + pointwise 1x1 conv. (unchanged)
// ---------------------------------------------------------------------------
__global__ __launch_bounds__(256) void k5_pw(const float* __restrict__ out1d,
                                             const float* __restrict__ pw_w,
                                             const float* __restrict__ pw_b,
                                             float* __restrict__ out) {
  int gid = blockIdx.x * 256 + threadIdx.x;   // 131072 threads
  int b = gid >> 12;
  int p = gid & 4095;
  int h = p >> 6, w = p & 63;
  int hh = h >> 1, ww = w >> 1;
  int c1base = ((h & 1) << 1) | (w & 1);
  int n = hh * 32 + ww;
  float xs[18];
#pragma unroll
  for (int c = 0; c < 18; ++c)
    xs[c] = out1d[(b * C1 + c * 4 + c1base) * NTOK + n];
#pragma unroll
  for (int o = 0; o < 16; ++o) {
    float a = pw_b[o];
#pragma unroll
    for (int c = 0; c < 18; ++c) a += xs[c] * pw_w[o * 18 + c];
    out[((b * 16 + o) << 12) + p] = a;
  }
}

// ---------------------------------------------------------------------------
extern "C" void kernel_launch(void* const* d_in, const int* in_sizes, int n_in,
                              void* d_out, int out_size, void* d_ws, size_t ws_size,
                              hipStream_t stream) {
  (void)in_sizes; (void)n_in; (void)out_size; (void)ws_size;
  const float* x      = (const float*)d_in[0];
  const float* Wv     = (const float*)d_in[1];
  const float* bv     = (const float*)d_in[2];
  const float* conv_w = (const float*)d_in[3];
  const float* conv_b = (const float*)d_in[4];
  const float* pw_w   = (const float*)d_in[5];
  const float* pw_b   = (const float*)d_in[6];
  float* out = (float*)d_out;

  const size_t SZ_T = (size_t)BB * C1 * NTOK * sizeof(float);   // 9,437,184
  char* ws = (char*)d_ws;
  float* t     = (float*)(ws);
  float* tn    = (float*)(ws + SZ_T);
  float* v     = (float*)(ws + 2 * SZ_T);
  int*   idx   = (int*)  (ws + 3 * SZ_T);
  float* attn  = (float*)(ws + 3 * SZ_T + 393216);
  float* out1d = (float*)(ws + 3 * SZ_T + 2 * 393216);

  k1_build<<<dim3((BB * NTOK) / 128), 128, 0, stream>>>(x, t, tn);
  k2_vproj<<<dim3(576), 256, 0, stream>>>(t, Wv, bv, v);
  k3_topk <<<dim3(512), 512, 0, stream>>>(tn, idx, attn);
  k4_conv1d<<<dim3(512), 256, 0, stream>>>(v, idx, attn, conv_w, conv_b, out1d);
  k5_pw   <<<dim3((BB * 4096) / 256), 256, 0, stream>>>(out1d, pw_w, pw_b, out);
}

// Round 6
// 390.746 us; speedup vs baseline: 8.8810x; 8.8810x over previous
//
#include <hip/hip_runtime.h>
#include <math.h>

// Problem constants
#define BB   32
#define CIN  16
#define C1   72      // (16+2)*2*2
#define NTOK 1024    // 32*32
#define HH   64
#define WW2  64

// ---------------------------------------------------------------------------
// Kernel 1: coord-concat + pixel_unshuffle -> t [B,72,1024]; per-token
// channel-norm -> tn. One thread per (b, token). (unchanged)
// ---------------------------------------------------------------------------
__global__ __launch_bounds__(128) void k1_build(const float* __restrict__ x,
                                                float* __restrict__ t,
                                                float* __restrict__ tn) {
  int gid = blockIdx.x * 128 + threadIdx.x;   // 32768 threads
  int b = gid >> 10;
  int n = gid & 1023;
  int hh = n >> 5, ww = n & 31;
  float vals[C1];
  float ss = 0.f;
#pragma unroll
  for (int c1 = 0; c1 < C1; ++c1) {
    int c = c1 >> 2, sh = (c1 >> 1) & 1, sw = c1 & 1;
    int h = 2 * hh + sh, w = 2 * ww + sw;
    float val;
    if (c < CIN) {
      val = x[((b * CIN + c) * HH + h) * WW2 + w];
    } else {
      float r = fmaxf(sqrtf((float)(h * h + w * w)), 1e-12f);
      val = (c == CIN ? (float)h : (float)w) / r;
    }
    vals[c1] = val;
    ss += val * val;
  }
  float inv = 1.0f / fmaxf(sqrtf(ss), 1e-12f);
#pragma unroll
  for (int c1 = 0; c1 < C1; ++c1) {
    int o = (b * C1 + c1) * NTOK + n;
    t[o]  = vals[c1];
    tn[o] = vals[c1] * inv;
  }
}

// ---------------------------------------------------------------------------
// Kernel 2 (v3): V = t @ Wv^T + bv. EXACT round-4 structure (BK=16, [64][20]
// LDS, 4x4 micro-tile, 80 VGPR, no spill, 132us) + the k3-proven two-barrier
// register prefetch (T14): next K-tile loads (2 float4, +8 VGPR) issue BEFORE
// the compute phase; LDS write after the consume-barrier. #pragma unroll 1 on
// the K-loop -- spill discipline: <=32 b128 results in flight (round-5's
// BK=32 full-unroll had 64 -> 16 GB scratch traffic).
// ---------------------------------------------------------------------------
#define K2_BK 16
#define K2_LD 20
__global__ __launch_bounds__(256) void k2_vproj(const float* __restrict__ A,
                                                const float* __restrict__ Wv,
                                                const float* __restrict__ bv,
                                                float* __restrict__ V) {
  __shared__ float As[64][K2_LD];
  __shared__ float Bs[64][K2_LD];
  int wg = blockIdx.x;                  // 0..575
  int xcd = wg & 7;
  int q = wg >> 3;                      // 0..71
  int row0 = (q >> 1) * 64;             // 36 row tiles
  int col0 = (xcd * 2 + (q & 1)) * 64;  // 16 col tiles, 2 per XCD
  int tid = threadIdx.x;
  int tx = tid & 15, ty = tid >> 4;
  int lr = tid >> 2;                    // 0..63
  int lk = (tid & 3) << 2;              // 0,4,8,12
  const float* Ap = A  + (row0 + lr) * 1024 + lk;
  const float* Bp = Wv + (col0 + lr) * 1024 + lk;

  // prologue: stage K-step 0
  float4 pa = *(const float4*)Ap;
  float4 pb = *(const float4*)Bp;
  *(float4*)&As[lr][lk] = pa;
  *(float4*)&Bs[lr][lk] = pb;

  float acc[4][4];
#pragma unroll
  for (int i = 0; i < 4; ++i)
#pragma unroll
    for (int j = 0; j < 4; ++j) acc[i][j] = 0.f;
  __syncthreads();

#pragma unroll 1
  for (int s = 0; s < 64; ++s) {
    if (s < 63) {                       // issue next K-tile loads (no use yet)
      pa = *(const float4*)(Ap + (s + 1) * K2_BK);
      pb = *(const float4*)(Bp + (s + 1) * K2_BK);
    }
#pragma unroll
    for (int kq = 0; kq < K2_BK; kq += 4) {
      float4 av[4], bvv[4];
#pragma unroll
      for (int i = 0; i < 4; ++i) av[i] = *(const float4*)&As[ty * 4 + i][kq];
#pragma unroll
      for (int j = 0; j < 4; ++j) bvv[j] = *(const float4*)&Bs[tx + 16 * j][kq];
#pragma unroll
      for (int i = 0; i < 4; ++i)
#pragma unroll
        for (int j = 0; j < 4; ++j)
          acc[i][j] += av[i].x * bvv[j].x + av[i].y * bvv[j].y +
                       av[i].z * bvv[j].z + av[i].w * bvv[j].w;
    }
    __syncthreads();                    // all LDS reads of this tile done
    if (s < 63) {                       // write prefetched tile (vmcnt waits
      *(float4*)&As[lr][lk] = pa;       //  here, hidden under the compute)
      *(float4*)&Bs[lr][lk] = pb;
    }
    __syncthreads();                    // new tile visible
  }
#pragma unroll
  for (int i = 0; i < 4; ++i) {
    int r = row0 + ty * 4 + i;
#pragma unroll
    for (int j = 0; j < 4; ++j) {
      int cidx = col0 + tx + 16 * j;
      V[r * 1024 + cidx] = acc[i][j] + bv[cidx];
    }
  }
}

// ---------------------------------------------------------------------------
// Kernel 3 (v4, unchanged): cosine-sim + online top-3 + softmax.
// 512 thr = 16 ty x 32 tx, 4x4 per thread, 64 rows x 8 x 128-col tiles,
// skip-max guard, XCD swizzle, register prefetch of next btile.
// ---------------------------------------------------------------------------
#define INS(TV, TI, d, di)                                              \
  {                                                                     \
    if ((d) > TV[0] || ((d) == TV[0] && (di) < TI[0])) {                \
      TV[2] = TV[1]; TI[2] = TI[1];                                     \
      TV[1] = TV[0]; TI[1] = TI[0];                                     \
      TV[0] = (d);   TI[0] = (di);                                      \
    } else if ((d) > TV[1] || ((d) == TV[1] && (di) < TI[1])) {         \
      TV[2] = TV[1]; TI[2] = TI[1];                                     \
      TV[1] = (d);   TI[1] = (di);                                      \
    } else if ((d) > TV[2] || ((d) == TV[2] && (di) < TI[2])) {         \
      TV[2] = (d);   TI[2] = (di);                                      \
    }                                                                   \
  }

__global__ __launch_bounds__(512, 4) void k3_topk(const float* __restrict__ tn,
                                                  int* __restrict__ idxo,
                                                  float* __restrict__ attno) {
  __shared__ float smem[C1 * 64 + C1 * 128];   // arow | btile, 55.3 KB
  float* arow  = smem;              // [C1][64]
  float* btile = smem + C1 * 64;    // [C1][128]

  int wg = blockIdx.x;              // 0..511
  int xcd = wg & 7;
  int q = wg >> 3;                  // 0..63
  int b  = xcd * 4 + (q >> 4);      // 4 batches per XCD
  int n0 = (q & 15) * 64;
  int tid = threadIdx.x;
  int tx = tid & 31;   // col group: cols tx*4..+3 (of 128)
  int ty = tid >> 5;   // row group: rows ty*4..+3 (of 64)

  const float* gbase = tn + b * C1 * NTOK;

  // per-thread staging slots for btile: 2304 float4 / 512 thr = 4.5
  int t0 = tid, t1 = tid + 512, t2 = tid + 1024, t3 = tid + 1536, t4 = tid + 2048;
  int go0 = (t0 >> 5) * NTOK + (t0 & 31) * 4, lo0 = (t0 >> 5) * 128 + (t0 & 31) * 4;
  int go1 = (t1 >> 5) * NTOK + (t1 & 31) * 4, lo1 = (t1 >> 5) * 128 + (t1 & 31) * 4;
  int go2 = (t2 >> 5) * NTOK + (t2 & 31) * 4, lo2 = (t2 >> 5) * 128 + (t2 & 31) * 4;
  int go3 = (t3 >> 5) * NTOK + (t3 & 31) * 4, lo3 = (t3 >> 5) * 128 + (t3 & 31) * 4;
  int go4 = (t4 >> 5) * NTOK + (t4 & 31) * 4, lo4 = (t4 >> 5) * 128 + (t4 & 31) * 4;
  bool has4 = (t4 < C1 * 32);       // tid < 256

  // stage this block's 64 rows (72 channels)
  for (int e4 = tid; e4 < C1 * 16; e4 += 512) {
    int c = e4 >> 4, qq = e4 & 15;
    *(float4*)&arow[c * 64 + qq * 4] =
        *(const float4*)&tn[(b * C1 + c) * NTOK + n0 + qq * 4];
  }
  // stage btile tile 0 directly
  {
    *(float4*)&btile[lo0] = *(const float4*)&gbase[go0];
    *(float4*)&btile[lo1] = *(const float4*)&gbase[go1];
    *(float4*)&btile[lo2] = *(const float4*)&gbase[go2];
    *(float4*)&btile[lo3] = *(const float4*)&gbase[go3];
    if (has4) *(float4*)&btile[lo4] = *(const float4*)&gbase[go4];
  }

  float tv[4][3];
  int   ti[4][3];
#pragma unroll
  for (int ri = 0; ri < 4; ++ri) {
    tv[ri][0] = tv[ri][1] = tv[ri][2] = -INFINITY;
    ti[ri][0] = ti[ri][1] = ti[ri][2] = 0x7fffffff;
  }
  __syncthreads();

#pragma unroll 1
  for (int tl = 0; tl < 8; ++tl) {
    // issue next-tile loads (values not used until after the barrier)
    float4 p0, p1, p2, p3, p4;
    if (tl < 7) {
      const float* gb = gbase + (tl + 1) * 128;
      p0 = *(const float4*)&gb[go0];
      p1 = *(const float4*)&gb[go1];
      p2 = *(const float4*)&gb[go2];
      p3 = *(const float4*)&gb[go3];
      if (has4) p4 = *(const float4*)&gb[go4];
    }

    int m0 = tl * 128;
    float4 acc0 = {0,0,0,0}, acc1 = {0,0,0,0}, acc2 = {0,0,0,0}, acc3 = {0,0,0,0};
#pragma unroll 4
    for (int c = 0; c < C1; ++c) {
      float4 av  = *(const float4*)&arow[c * 64 + ty * 4];
      float4 bv4 = *(const float4*)&btile[c * 128 + tx * 4];
      acc0.x += av.x * bv4.x; acc0.y += av.x * bv4.y;
      acc0.z += av.x * bv4.z; acc0.w += av.x * bv4.w;
      acc1.x += av.y * bv4.x; acc1.y += av.y * bv4.y;
      acc1.z += av.y * bv4.z; acc1.w += av.y * bv4.w;
      acc2.x += av.z * bv4.x; acc2.y += av.z * bv4.y;
      acc2.z += av.z * bv4.z; acc2.w += av.z * bv4.w;
      acc3.x += av.w * bv4.x; acc3.y += av.w * bv4.y;
      acc3.z += av.w * bv4.z; acc3.w += av.w * bv4.w;
    }
    int cb = m0 + tx * 4;
    float mx;
    mx = fmaxf(fmaxf(acc0.x, acc0.y), fmaxf(acc0.z, acc0.w));
    if (mx > tv[0][2]) {
      INS(tv[0], ti[0], acc0.x, cb + 0); INS(tv[0], ti[0], acc0.y, cb + 1);
      INS(tv[0], ti[0], acc0.z, cb + 2); INS(tv[0], ti[0], acc0.w, cb + 3);
    }
    mx = fmaxf(fmaxf(acc1.x, acc1.y), fmaxf(acc1.z, acc1.w));
    if (mx > tv[1][2]) {
      INS(tv[1], ti[1], acc1.x, cb + 0); INS(tv[1], ti[1], acc1.y, cb + 1);
      INS(tv[1], ti[1], acc1.z, cb + 2); INS(tv[1], ti[1], acc1.w, cb + 3);
    }
    mx = fmaxf(fmaxf(acc2.x, acc2.y), fmaxf(acc2.z, acc2.w));
    if (mx > tv[2][2]) {
      INS(tv[2], ti[2], acc2.x, cb + 0); INS(tv[2], ti[2], acc2.y, cb + 1);
      INS(tv[2], ti[2], acc2.z, cb + 2); INS(tv[2], ti[2], acc2.w, cb + 3);
    }
    mx = fmaxf(fmaxf(acc3.x, acc3.y), fmaxf(acc3.z, acc3.w));
    if (mx > tv[3][2]) {
      INS(tv[3], ti[3], acc3.x, cb + 0); INS(tv[3], ti[3], acc3.y, cb + 1);
      INS(tv[3], ti[3], acc3.z, cb + 2); INS(tv[3], ti[3], acc3.w, cb + 3);
    }

    __syncthreads();               // all btile reads done
    if (tl < 7) {
      *(float4*)&btile[lo0] = p0;
      *(float4*)&btile[lo1] = p1;
      *(float4*)&btile[lo2] = p2;
      *(float4*)&btile[lo3] = p3;
      if (has4) *(float4*)&btile[lo4] = p4;
    }
    __syncthreads();               // new tile visible
  }

  // merge 32 col-groups x 3 per row; reuse smem (staging done)
  float* mv = smem;                  // 64*32*3 = 6144 floats
  int*   mi = (int*)(smem + 6144);   // 6144 ints (12288 <= 13824)
#pragma unroll
  for (int ri = 0; ri < 4; ++ri) {
    int row = ty * 4 + ri;
#pragma unroll
    for (int j = 0; j < 3; ++j) {
      mv[(row * 32 + tx) * 3 + j] = tv[ri][j];
      mi[(row * 32 + tx) * 3 + j] = ti[ri][j];
    }
  }
  __syncthreads();
  if (tid < 64) {
    float fv[3] = {-INFINITY, -INFINITY, -INFINITY};
    int   fi[3] = {0x7fffffff, 0x7fffffff, 0x7fffffff};
    for (int g = 0; g < 32; ++g) {
#pragma unroll
      for (int j = 0; j < 3; ++j) {
        float d  = mv[(tid * 32 + g) * 3 + j];
        int   di = mi[(tid * 32 + g) * 3 + j];
        INS(fv, fi, d, di);
      }
    }
    float e1 = expf(fv[1] - fv[0]), e2 = expf(fv[2] - fv[0]);
    float inv = 1.0f / (1.0f + e1 + e2);
    int ob = (b * NTOK + n0 + tid) * 3;
    idxo[ob] = fi[0]; idxo[ob + 1] = fi[1]; idxo[ob + 2] = fi[2];
    attno[ob] = inv; attno[ob + 1] = e1 * inv; attno[ob + 2] = e2 * inv;
  }
}

// ---------------------------------------------------------------------------
// Kernel 4: gather top-3 neighbor value columns (x attn) into LDS, then
// conv1d(kernel=K,stride=K) == [72 x 216] GEMM per token. (unchanged)
// ---------------------------------------------------------------------------
__global__ __launch_bounds__(256) void k4_conv1d(const float* __restrict__ v,
                                                 const int* __restrict__ idx,
                                                 const float* __restrict__ attn,
                                                 const float* __restrict__ conv_w,
                                                 const float* __restrict__ conv_b,
                                                 float* __restrict__ out1d) {
  __shared__ float prime[64][220];
  __shared__ int   sidx[64][3];
  __shared__ float satt[64][3];
  int wg = blockIdx.x;              // 0..511
  int xcd = wg & 7;
  int q = wg >> 3;                  // 0..63
  int b  = xcd * 4 + (q >> 4);
  int n0 = (q & 15) * 64;
  int tid = threadIdx.x;
  if (tid < 192) {
    int tok = tid / 3, k = tid % 3;
    sidx[tok][k] = idx[(b * NTOK + n0 + tok) * 3 + k];
    satt[tok][k] = attn[(b * NTOK + n0 + tok) * 3 + k];
  }
  __syncthreads();
  for (int e = tid; e < 64 * 216; e += 256) {
    int tok = e & 63, ck = e >> 6;
    int c = ck / 3, k = ck - c * 3;
    prime[tok][ck] = v[(b * C1 + c) * NTOK + sidx[tok][k]] * satt[tok][k];
  }
  __syncthreads();
  int tok = tid & 63;
  int obase = __builtin_amdgcn_readfirstlane((int)(tid >> 6)) * 18;
  float acc[18];
#pragma unroll
  for (int j = 0; j < 18; ++j) acc[j] = 0.f;
  for (int ck4 = 0; ck4 < 54; ++ck4) {
    float4 p4 = *(const float4*)&prime[tok][ck4 * 4];
#pragma unroll
    for (int j = 0; j < 18; ++j) {
      float4 w4 = *(const float4*)&conv_w[(obase + j) * 216 + ck4 * 4];
      acc[j] += p4.x * w4.x + p4.y * w4.y + p4.z * w4.z + p4.w * w4.w;
    }
  }
#pragma unroll
  for (int j = 0; j < 18; ++j) {
    int o = obase + j;
    out1d[(b * C1 + o) * NTOK + n0 + tok] = acc[j] + conv_b[o];
  }
}

// ---------------------------------------------------------------------------
// Kernel 5: pixel_shuffle + pointwise 1x1 conv. (unchanged)
// ---------------------------------------------------------------------------
__global__ __launch_bounds__(256) void k5_pw(const float* __restrict__ out1d,
                                             const float* __restrict__ pw_w,
                                             const float* __restrict__ pw_b,
                                             float* __restrict__ out) {
  int gid = blockIdx.x * 256 + threadIdx.x;   // 131072 threads
  int b = gid >> 12;
  int p = gid & 4095;
  int h = p >> 6, w = p & 63;
  int hh = h >> 1, ww = w >> 1;
  int c1base = ((h & 1) << 1) | (w & 1);
  int n = hh * 32 + ww;
  float xs[18];
#pragma unroll
  for (int c = 0; c < 18; ++c)
    xs[c] = out1d[(b * C1 + c * 4 + c1base) * NTOK + n];
#pragma unroll
  for (int o = 0; o < 16; ++o) {
    float a = pw_b[o];
#pragma unroll
    for (int c = 0; c < 18; ++c) a += xs[c] * pw_w[o * 18 + c];
    out[((b * 16 + o) << 12) + p] = a;
  }
}

// ---------------------------------------------------------------------------
extern "C" void kernel_launch(void* const* d_in, const int* in_sizes, int n_in,
                              void* d_out, int out_size, void* d_ws, size_t ws_size,
                              hipStream_t stream) {
  (void)in_sizes; (void)n_in; (void)out_size; (void)ws_size;
  const float* x      = (const float*)d_in[0];
  const float* Wv     = (const float*)d_in[1];
  const float* bv     = (const float*)d_in[2];
  const float* conv_w = (const float*)d_in[3];
  const float* conv_b = (const float*)d_in[4];
  const float* pw_w   = (const float*)d_in[5];
  const float* pw_b   = (const float*)d_in[6];
  float* out = (float*)d_out;

  const size_t SZ_T = (size_t)BB * C1 * NTOK * sizeof(float);   // 9,437,184
  char* ws = (char*)d_ws;
  float* t     = (float*)(ws);
  float* tn    = (float*)(ws + SZ_T);
  float* v     = (float*)(ws + 2 * SZ_T);
  int*   idx   = (int*)  (ws + 3 * SZ_T);
  float* attn  = (float*)(ws + 3 * SZ_T + 393216);
  float* out1d = (float*)(ws + 3 * SZ_T + 2 * 393216);

  k1_build<<<dim3((BB * NTOK) / 128), 128, 0, stream>>>(x, t, tn);
  k2_vproj<<<dim3(576), 256, 0, stream>>>(t, Wv, bv, v);
  k3_topk <<<dim3(512), 512, 0, stream>>>(tn, idx, attn);
  k4_conv1d<<<dim3(512), 256, 0, stream>>>(v, idx, attn, conv_w, conv_b, out1d);
  k5_pw   <<<dim3((BB * 4096) / 256), 256, 0, stream>>>(out1d, pw_w, pw_b, out);
}

// Round 8
// 381.352 us; speedup vs baseline: 9.0998x; 1.0246x over previous
//
#include <hip/hip_runtime.h>
#include <math.h>

// Problem constants
#define BB   32
#define CIN  16
#define C1   72      // (16+2)*2*2
#define NTOK 1024    // 32*32
#define HH   64
#define WW2  64

// ---------------------------------------------------------------------------
// Kernel 1: coord-concat + pixel_unshuffle -> t [B,72,1024]; per-token
// channel-norm -> tn. One thread per (b, token). (unchanged)
// ---------------------------------------------------------------------------
__global__ __launch_bounds__(128) void k1_build(const float* __restrict__ x,
                                                float* __restrict__ t,
                                                float* __restrict__ tn) {
  int gid = blockIdx.x * 128 + threadIdx.x;   // 32768 threads
  int b = gid >> 10;
  int n = gid & 1023;
  int hh = n >> 5, ww = n & 31;
  float vals[C1];
  float ss = 0.f;
#pragma unroll
  for (int c1 = 0; c1 < C1; ++c1) {
    int c = c1 >> 2, sh = (c1 >> 1) & 1, sw = c1 & 1;
    int h = 2 * hh + sh, w = 2 * ww + sw;
    float val;
    if (c < CIN) {
      val = x[((b * CIN + c) * HH + h) * WW2 + w];
    } else {
      float r = fmaxf(sqrtf((float)(h * h + w * w)), 1e-12f);
      val = (c == CIN ? (float)h : (float)w) / r;
    }
    vals[c1] = val;
    ss += val * val;
  }
  float inv = 1.0f / fmaxf(sqrtf(ss), 1e-12f);
#pragma unroll
  for (int c1 = 0; c1 < C1; ++c1) {
    int o = (b * C1 + c1) * NTOK + n;
    t[o]  = vals[c1];
    tn[o] = vals[c1] * inv;
  }
}

// ---------------------------------------------------------------------------
// Kernel 2 (v4): V = t @ Wv^T + bv. Proven round-6 config (BK=16, 4x4
// micro-tile, prefetch regs, unroll-1 outer, <=32 b128 in flight) with:
//  - double-buffered LDS (2x10KB): ONE barrier per K-step (was 2).
//  - epilogue stores TOKEN-MAJOR v_t[b][token][72] so k4's gather is
//    coalesced (stores scatter 4B but L2 absorbs; sectors end fully dirty).
// ---------------------------------------------------------------------------
#define K2_BK 16
#define K2_LD 20
__global__ __launch_bounds__(256) void k2_vproj(const float* __restrict__ A,
                                                const float* __restrict__ Wv,
                                                const float* __restrict__ bv,
                                                float* __restrict__ v_t) {
  __shared__ float As[2][64][K2_LD];
  __shared__ float Bs[2][64][K2_LD];
  int wg = blockIdx.x;                  // 0..575
  int xcd = wg & 7;
  int q = wg >> 3;                      // 0..71
  int row0 = (q >> 1) * 64;             // 36 row tiles
  int col0 = (xcd * 2 + (q & 1)) * 64;  // 16 col tiles, 2 per XCD
  int tid = threadIdx.x;
  int tx = tid & 15, ty = tid >> 4;
  int lr = tid >> 2;                    // 0..63
  int lk = (tid & 3) << 2;              // 0,4,8,12
  const float* Ap = A  + (row0 + lr) * 1024 + lk;
  const float* Bp = Wv + (col0 + lr) * 1024 + lk;

  // prologue: stage K-step 0 into buffer 0
  float4 pa = *(const float4*)Ap;
  float4 pb = *(const float4*)Bp;
  *(float4*)&As[0][lr][lk] = pa;
  *(float4*)&Bs[0][lr][lk] = pb;

  float acc[4][4];
#pragma unroll
  for (int i = 0; i < 4; ++i)
#pragma unroll
    for (int j = 0; j < 4; ++j) acc[i][j] = 0.f;
  __syncthreads();

  int cur = 0;
#pragma unroll 1
  for (int s = 0; s < 64; ++s) {
    if (s < 63) {                       // issue next K-tile loads (no use yet)
      pa = *(const float4*)(Ap + (s + 1) * K2_BK);
      pb = *(const float4*)(Bp + (s + 1) * K2_BK);
    }
#pragma unroll
    for (int kq = 0; kq < K2_BK; kq += 4) {
      float4 av[4], bvv[4];
#pragma unroll
      for (int i = 0; i < 4; ++i) av[i] = *(const float4*)&As[cur][ty * 4 + i][kq];
#pragma unroll
      for (int j = 0; j < 4; ++j) bvv[j] = *(const float4*)&Bs[cur][tx + 16 * j][kq];
#pragma unroll
      for (int i = 0; i < 4; ++i)
#pragma unroll
        for (int j = 0; j < 4; ++j)
          acc[i][j] += av[i].x * bvv[j].x + av[i].y * bvv[j].y +
                       av[i].z * bvv[j].z + av[i].w * bvv[j].w;
    }
    if (s < 63) {                       // write next tile to the OTHER buffer
      *(float4*)&As[cur ^ 1][lr][lk] = pa;   // (no reader of it yet -> no
      *(float4*)&Bs[cur ^ 1][lr][lk] = pb;   //  pre-write barrier needed)
    }
    __syncthreads();                    // next buffer visible / cur reads done
    cur ^= 1;
  }
  // token-major store: v_t[(b*1024 + token)*72 + c]
#pragma unroll
  for (int i = 0; i < 4; ++i) {
    int r = row0 + ty * 4 + i;          // global row = b*72 + c
    int bb = r / 72;
    int cc = r - bb * 72;
#pragma unroll
    for (int j = 0; j < 4; ++j) {
      int cidx = col0 + tx + 16 * j;
      v_t[(bb * NTOK + cidx) * C1 + cc] = acc[i][j] + bv[cidx];
    }
  }
}

// ---------------------------------------------------------------------------
// Kernel 3 (v3): cosine-sim + online top-3 + softmax.
// Round-4 config: 512 thr = 16 ty x 32 tx, 4x4 per thread, 64 rows x
// 8 x 128-col tiles, skip-max guard, XCD swizzle, stage-after-barrier.
// (register-prefetch variant measured SLOWER: 145.6 vs 131.9 us -> reverted.)
// ---------------------------------------------------------------------------
#define INS(TV, TI, d, di)                                              \
  {                                                                     \
    if ((d) > TV[0] || ((d) == TV[0] && (di) < TI[0])) {                \
      TV[2] = TV[1]; TI[2] = TI[1];                                     \
      TV[1] = TV[0]; TI[1] = TI[0];                                     \
      TV[0] = (d);   TI[0] = (di);                                      \
    } else if ((d) > TV[1] || ((d) == TV[1] && (di) < TI[1])) {         \
      TV[2] = TV[1]; TI[2] = TI[1];                                     \
      TV[1] = (d);   TI[1] = (di);                                      \
    } else if ((d) > TV[2] || ((d) == TV[2] && (di) < TI[2])) {         \
      TV[2] = (d);   TI[2] = (di);                                      \
    }                                                                   \
  }

__global__ __launch_bounds__(512, 4) void k3_topk(const float* __restrict__ tn,
                                                  int* __restrict__ idxo,
                                                  float* __restrict__ attno) {
  __shared__ float smem[C1 * 64 + C1 * 128];   // arow | btile, 55.3 KB
  float* arow  = smem;              // [C1][64]
  float* btile = smem + C1 * 64;    // [C1][128]

  int wg = blockIdx.x;              // 0..511
  int xcd = wg & 7;
  int q = wg >> 3;                  // 0..63
  int b  = xcd * 4 + (q >> 4);      // 4 batches per XCD
  int n0 = (q & 15) * 64;
  int tid = threadIdx.x;
  int tx = tid & 31;   // col group: cols tx*4..+3 (of 128)
  int ty = tid >> 5;   // row group: rows ty*4..+3 (of 64)

  // stage this block's 64 rows (72 channels)
  for (int e4 = tid; e4 < C1 * 16; e4 += 512) {
    int c = e4 >> 4, qq = e4 & 15;
    *(float4*)&arow[c * 64 + qq * 4] =
        *(const float4*)&tn[(b * C1 + c) * NTOK + n0 + qq * 4];
  }

  float tv[4][3];
  int   ti[4][3];
#pragma unroll
  for (int ri = 0; ri < 4; ++ri) {
    tv[ri][0] = tv[ri][1] = tv[ri][2] = -INFINITY;
    ti[ri][0] = ti[ri][1] = ti[ri][2] = 0x7fffffff;
  }

#pragma unroll 1
  for (int tl = 0; tl < 8; ++tl) {
    int m0 = tl * 128;
    __syncthreads();   // previous tile fully consumed (covers arow staging)
    for (int e4 = tid; e4 < C1 * 32; e4 += 512) {
      int c = e4 >> 5, qq = e4 & 31;
      *(float4*)&btile[c * 128 + qq * 4] =
          *(const float4*)&tn[(b * C1 + c) * NTOK + m0 + qq * 4];
    }
    __syncthreads();

    float4 acc0 = {0,0,0,0}, acc1 = {0,0,0,0}, acc2 = {0,0,0,0}, acc3 = {0,0,0,0};
#pragma unroll 4
    for (int c = 0; c < C1; ++c) {
      float4 av  = *(const float4*)&arow[c * 64 + ty * 4];
      float4 bv4 = *(const float4*)&btile[c * 128 + tx * 4];
      acc0.x += av.x * bv4.x; acc0.y += av.x * bv4.y;
      acc0.z += av.x * bv4.z; acc0.w += av.x * bv4.w;
      acc1.x += av.y * bv4.x; acc1.y += av.y * bv4.y;
      acc1.z += av.y * bv4.z; acc1.w += av.y * bv4.w;
      acc2.x += av.z * bv4.x; acc2.y += av.z * bv4.y;
      acc2.z += av.z * bv4.z; acc2.w += av.z * bv4.w;
      acc3.x += av.w * bv4.x; acc3.y += av.w * bv4.y;
      acc3.z += av.w * bv4.z; acc3.w += av.w * bv4.w;
    }
    int cb = m0 + tx * 4;
    float mx;
    mx = fmaxf(fmaxf(acc0.x, acc0.y), fmaxf(acc0.z, acc0.w));
    if (mx > tv[0][2]) {
      INS(tv[0], ti[0], acc0.x, cb + 0); INS(tv[0], ti[0], acc0.y, cb + 1);
      INS(tv[0], ti[0], acc0.z, cb + 2); INS(tv[0], ti[0], acc0.w, cb + 3);
    }
    mx = fmaxf(fmaxf(acc1.x, acc1.y), fmaxf(acc1.z, acc1.w));
    if (mx > tv[1][2]) {
      INS(tv[1], ti[1], acc1.x, cb + 0); INS(tv[1], ti[1], acc1.y, cb + 1);
      INS(tv[1], ti[1], acc1.z, cb + 2); INS(tv[1], ti[1], acc1.w, cb + 3);
    }
    mx = fmaxf(fmaxf(acc2.x, acc2.y), fmaxf(acc2.z, acc2.w));
    if (mx > tv[2][2]) {
      INS(tv[2], ti[2], acc2.x, cb + 0); INS(tv[2], ti[2], acc2.y, cb + 1);
      INS(tv[2], ti[2], acc2.z, cb + 2); INS(tv[2], ti[2], acc2.w, cb + 3);
    }
    mx = fmaxf(fmaxf(acc3.x, acc3.y), fmaxf(acc3.z, acc3.w));
    if (mx > tv[3][2]) {
      INS(tv[3], ti[3], acc3.x, cb + 0); INS(tv[3], ti[3], acc3.y, cb + 1);
      INS(tv[3], ti[3], acc3.z, cb + 2); INS(tv[3], ti[3], acc3.w, cb + 3);
    }
  }

  // merge 32 col-groups x 3 per row; reuse smem (staging done)
  __syncthreads();
  float* mv = smem;                  // 64*32*3 = 6144 floats
  int*   mi = (int*)(smem + 6144);   // 6144 ints (12288 <= 13824)
#pragma unroll
  for (int ri = 0; ri < 4; ++ri) {
    int row = ty * 4 + ri;
#pragma unroll
    for (int j = 0; j < 3; ++j) {
      mv[(row * 32 + tx) * 3 + j] = tv[ri][j];
      mi[(row * 32 + tx) * 3 + j] = ti[ri][j];
    }
  }
  __syncthreads();
  if (tid < 64) {
    float fv[3] = {-INFINITY, -INFINITY, -INFINITY};
    int   fi[3] = {0x7fffffff, 0x7fffffff, 0x7fffffff};
    for (int g = 0; g < 32; ++g) {
#pragma unroll
      for (int j = 0; j < 3; ++j) {
        float d  = mv[(tid * 32 + g) * 3 + j];
        int   di = mi[(tid * 32 + g) * 3 + j];
        INS(fv, fi, d, di);
      }
    }
    float e1 = expf(fv[1] - fv[0]), e2 = expf(fv[2] - fv[0]);
    float inv = 1.0f / (1.0f + e1 + e2);
    int ob = (b * NTOK + n0 + tid) * 3;
    idxo[ob] = fi[0]; idxo[ob + 1] = fi[1]; idxo[ob + 2] = fi[2];
    attno[ob] = inv; attno[ob + 1] = e1 * inv; attno[ob + 2] = e2 * inv;
  }
}

// ---------------------------------------------------------------------------
// Kernel 4 (v2): gather via TOKEN-MAJOR v_t -> coalesced 288B runs
// (18 float4 per (tok,k)), LDS writes 4x b32 stride-3 (conflict-free by
// coprimality). Compute phase identical to proven version.
// ---------------------------------------------------------------------------
__global__ __launch_bounds__(256) void k4_conv1d(const float* __restrict__ v_t,
                                                 const int* __restrict__ idx,
                                                 const float* __restrict__ attn,
                                                 const float* __restrict__ conv_w,
                                                 const float* __restrict__ conv_b,
                                                 float* __restrict__ out1d) {
  __shared__ float prime[64][220];
  __shared__ int   sidx[64][3];
  __shared__ float satt[64][3];
  int wg = blockIdx.x;              // 0..511
  int xcd = wg & 7;
  int q = wg >> 3;                  // 0..63
  int b  = xcd * 4 + (q >> 4);
  int n0 = (q & 15) * 64;
  int tid = threadIdx.x;
  if (tid < 192) {
    int tok = tid / 3, k = tid % 3;
    sidx[tok][k] = idx[(b * NTOK + n0 + tok) * 3 + k];
    satt[tok][k] = attn[(b * NTOK + n0 + tok) * 3 + k];
  }
  __syncthreads();
  // 64 tok x 3 k x 18 float4-of-c = 3456 units
  for (int u = tid; u < 64 * 3 * 18; u += 256) {
    int tok = u / 54;
    int r   = u - tok * 54;
    int k   = r / 18;
    int c4  = r - k * 18;
    float4 val = *(const float4*)&v_t[(b * NTOK + sidx[tok][k]) * C1 + c4 * 4];
    float s = satt[tok][k];
    int base = (c4 * 4) * 3 + k;          // position c*3+k
    prime[tok][base]     = val.x * s;
    prime[tok][base + 3] = val.y * s;
    prime[tok][base + 6] = val.z * s;
    prime[tok][base + 9] = val.w * s;
  }
  __syncthreads();
  int tok = tid & 63;
  int obase = __builtin_amdgcn_readfirstlane((int)(tid >> 6)) * 18;
  float acc[18];
#pragma unroll
  for (int j = 0; j < 18; ++j) acc[j] = 0.f;
  for (int ck4 = 0; ck4 < 54; ++ck4) {
    float4 p4 = *(const float4*)&prime[tok][ck4 * 4];
#pragma unroll
    for (int j = 0; j < 18; ++j) {
      float4 w4 = *(const float4*)&conv_w[(obase + j) * 216 + ck4 * 4];
      acc[j] += p4.x * w4.x + p4.y * w4.y + p4.z * w4.z + p4.w * w4.w;
    }
  }
#pragma unroll
  for (int j = 0; j < 18; ++j) {
    int o = obase + j;
    out1d[(b * C1 + o) * NTOK + n0 + tok] = acc[j] + conv_b[o];
  }
}

// ---------------------------------------------------------------------------
// Kernel 5: pixel_shuffle + pointwise 1x1 conv. (unchanged)
// ---------------------------------------------------------------------------
__global__ __launch_bounds__(256) void k5_pw(const float* __restrict__ out1d,
                                             const float* __restrict__ pw_w,
                                             const float* __restrict__ pw_b,
                                             float* __restrict__ out) {
  int gid = blockIdx.x * 256 + threadIdx.x;   // 131072 threads
  int b = gid >> 12;
  int p = gid & 4095;
  int h = p >> 6, w = p & 63;
  int hh = h >> 1, ww = w >> 1;
  int c1base = ((h & 1) << 1) | (w & 1);
  int n = hh * 32 + ww;
  float xs[18];
#pragma unroll
  for (int c = 0; c < 18; ++c)
    xs[c] = out1d[(b * C1 + c * 4 + c1base) * NTOK + n];
#pragma unroll
  for (int o = 0; o < 16; ++o) {
    float a = pw_b[o];
#pragma unroll
    for (int c = 0; c < 18; ++c) a += xs[c] * pw_w[o * 18 + c];
    out[((b * 16 + o) << 12) + p] = a;
  }
}

// ---------------------------------------------------------------------------
extern "C" void kernel_launch(void* const* d_in, const int* in_sizes, int n_in,
                              void* d_out, int out_size, void* d_ws, size_t ws_size,
                              hipStream_t stream) {
  (void)in_sizes; (void)n_in; (void)out_size; (void)ws_size;
  const float* x      = (const float*)d_in[0];
  const float* Wv     = (const float*)d_in[1];
  const float* bv     = (const float*)d_in[2];
  const float* conv_w = (const float*)d_in[3];
  const float* conv_b = (const float*)d_in[4];
  const float* pw_w   = (const float*)d_in[5];
  const float* pw_b   = (const float*)d_in[6];
  float* out = (float*)d_out;

  const size_t SZ_T = (size_t)BB * C1 * NTOK * sizeof(float);   // 9,437,184
  char* ws = (char*)d_ws;
  float* t     = (float*)(ws);
  float* tn    = (float*)(ws + SZ_T);
  float* v_t   = (float*)(ws + 2 * SZ_T);          // token-major [B][N][72]
  int*   idx   = (int*)  (ws + 3 * SZ_T);
  float* attn  = (float*)(ws + 3 * SZ_T + 393216);
  float* out1d = (float*)(ws + 3 * SZ_T + 2 * 393216);

  k1_build<<<dim3((BB * NTOK) / 128), 128, 0, stream>>>(x, t, tn);
  k2_vproj<<<dim3(576), 256, 0, stream>>>(t, Wv, bv, v_t);
  k3_topk <<<dim3(512), 512, 0, stream>>>(tn, idx, attn);
  k4_conv1d<<<dim3(512), 256, 0, stream>>>(v_t, idx, attn, conv_w, conv_b, out1d);
  k5_pw   <<<dim3((BB * 4096) / 256), 256, 0, stream>>>(out1d, pw_w, pw_b, out);
}

// Round 9
// 306.958 us; speedup vs baseline: 11.3052x; 1.2424x over previous
//
#include <hip/hip_runtime.h>
#include <math.h>

// Problem constants
#define BB   32
#define CIN  16
#define C1   72      // (16+2)*2*2
#define NTOK 1024    // 32*32
#define HH   64
#define WW2  64

typedef float f32x4 __attribute__((ext_vector_type(4)));
typedef short s16x8 __attribute__((ext_vector_type(8)));
typedef short s16x4 __attribute__((ext_vector_type(4)));

// bf16 helpers (bit-ops; avoids hip_bf16 header/version friction). RNE.
__device__ __forceinline__ unsigned short f2bf(float f) {
  unsigned int u = __float_as_uint(f);
  unsigned int r = (u + 0x7FFFu + ((u >> 16) & 1u)) >> 16;
  return (unsigned short)r;
}
__device__ __forceinline__ float bf2f(unsigned short s) {
  return __uint_as_float(((unsigned int)s) << 16);
}

// ---------------------------------------------------------------------------
// Kernel 0: Wv fp32 -> (wh, wl) bf16 split pair. 1024x1024 elements.
// ---------------------------------------------------------------------------
__global__ __launch_bounds__(256) void k0_wcvt(const float* __restrict__ Wv,
                                               short* __restrict__ wh,
                                               short* __restrict__ wl) {
  int i4 = (blockIdx.x * 256 + threadIdx.x) * 4;   // 1024 blocks covers 1M
  float4 v = *(const float4*)&Wv[i4];
  unsigned short h0 = f2bf(v.x), h1 = f2bf(v.y), h2 = f2bf(v.z), h3 = f2bf(v.w);
  s16x4 hv = { (short)h0, (short)h1, (short)h2, (short)h3 };
  s16x4 lv = { (short)f2bf(v.x - bf2f(h0)), (short)f2bf(v.y - bf2f(h1)),
               (short)f2bf(v.z - bf2f(h2)), (short)f2bf(v.w - bf2f(h3)) };
  *(s16x4*)&wh[i4] = hv;
  *(s16x4*)&wl[i4] = lv;
}

// ---------------------------------------------------------------------------
// Kernel 1: coord-concat + pixel_unshuffle; emits bf16 split pair (th, tl)
// for k2's MFMA, and fp32 tn for k3. One thread per (b, token).
// ---------------------------------------------------------------------------
__global__ __launch_bounds__(128) void k1_build(const float* __restrict__ x,
                                                short* __restrict__ th,
                                                short* __restrict__ tl,
                                                float* __restrict__ tn) {
  int gid = blockIdx.x * 128 + threadIdx.x;   // 32768 threads
  int b = gid >> 10;
  int n = gid & 1023;
  int hh = n >> 5, ww = n & 31;
  float vals[C1];
  float ss = 0.f;
#pragma unroll
  for (int c1 = 0; c1 < C1; ++c1) {
    int c = c1 >> 2, sh = (c1 >> 1) & 1, sw = c1 & 1;
    int h = 2 * hh + sh, w = 2 * ww + sw;
    float val;
    if (c < CIN) {
      val = x[((b * CIN + c) * HH + h) * WW2 + w];
    } else {
      float r = fmaxf(sqrtf((float)(h * h + w * w)), 1e-12f);
      val = (c == CIN ? (float)h : (float)w) / r;
    }
    vals[c1] = val;
    ss += val * val;
  }
  float inv = 1.0f / fmaxf(sqrtf(ss), 1e-12f);
#pragma unroll
  for (int c1 = 0; c1 < C1; ++c1) {
    int o = (b * C1 + c1) * NTOK + n;
    unsigned short h = f2bf(vals[c1]);
    th[o] = (short)h;
    tl[o] = (short)f2bf(vals[c1] - bf2f(h));
    tn[o] = vals[c1] * inv;
  }
}

// ---------------------------------------------------------------------------
// Kernel 2 (v5, MFMA): V = t @ Wv^T + bv via split-bf16, 3 products/step
// (hi*hi + hi*lo + lo*hi; lo*lo ~4e-6, dropped). 64x64 tile, 4 waves; wave w
// owns row-tile w (16 rows) x 4 col-tiles. mfma_f32_16x16x32_bf16:
//   A: row=lane&15, k=(lane>>4)*8+j;  B: col=lane&15, k=(lane>>4)*8+j;
//   D: col=lane&15, row=(lane>>4)*4+reg  [m89-verified].
// LDS holds fragments lane-linear (addr = (tile*64+lane)*16B) -> conflict-free
// ds_read_b128. Double-buffered, reg-prefetch (proven k2-v4 schedule).
// Was LDS-pipe-bound at 140us (fp32 needed 8 reads/64 FMA); now 10 reads
// feed 12 MFMAs -> ~20us LDS-bound floor.
// ---------------------------------------------------------------------------
#define K2S 32
__global__ __launch_bounds__(256) void k2_vproj(const short* __restrict__ th,
                                                const short* __restrict__ tl,
                                                const short* __restrict__ wh,
                                                const short* __restrict__ wl,
                                                const float* __restrict__ bv,
                                                float* __restrict__ v_t) {
  __shared__ short sA[2][2][2048];   // [buf][hi/lo][(rt*64+lane)*8] 16KB
  __shared__ short sB[2][2][2048];   // 16KB
  int wg = blockIdx.x;                  // 0..575, XCD-swizzled
  int xcd = wg & 7;
  int q = wg >> 3;
  int row0 = (q >> 1) * 64;             // 36 row tiles
  int col0 = (xcd * 2 + (q & 1)) * 64;  // 16 col tiles, 2 per XCD
  int tid = threadIdx.x;
  int wv = tid >> 6, lane = tid & 63;

  // staging: thread stages one 16B chunk per array: row=tid>>2, kchunk=tid&3
  int srow = tid >> 2, skc = tid & 3;
  int slot = (((srow >> 4) * 64) + (srow & 15) + 16 * skc) * 8;  // short idx
  const short* gAh = th + (row0 + srow) * 1024 + skc * 8;
  const short* gAl = tl + (row0 + srow) * 1024 + skc * 8;
  const short* gBh = wh + (col0 + srow) * 1024 + skc * 8;
  const short* gBl = wl + (col0 + srow) * 1024 + skc * 8;

  // prologue: K-step 0 into buffer 0
  s16x8 pah = *(const s16x8*)gAh;
  s16x8 pal = *(const s16x8*)gAl;
  s16x8 pbh = *(const s16x8*)gBh;
  s16x8 pbl = *(const s16x8*)gBl;
  *(s16x8*)&sA[0][0][slot] = pah;  *(s16x8*)&sA[0][1][slot] = pal;
  *(s16x8*)&sB[0][0][slot] = pbh;  *(s16x8*)&sB[0][1][slot] = pbl;

  f32x4 acc0 = {0,0,0,0}, acc1 = {0,0,0,0}, acc2 = {0,0,0,0}, acc3 = {0,0,0,0};
  __syncthreads();

  int cur = 0;
#pragma unroll 1
  for (int ks = 0; ks < 32; ++ks) {
    if (ks < 31) {                      // issue next K-step loads (no use yet)
      pah = *(const s16x8*)(gAh + (ks + 1) * K2S);
      pal = *(const s16x8*)(gAl + (ks + 1) * K2S);
      pbh = *(const s16x8*)(gBh + (ks + 1) * K2S);
      pbl = *(const s16x8*)(gBl + (ks + 1) * K2S);
    }
    s16x8 ah = *(const s16x8*)&sA[cur][0][(wv * 64 + lane) * 8];
    s16x8 al = *(const s16x8*)&sA[cur][1][(wv * 64 + lane) * 8];
#pragma unroll
    for (int ct = 0; ct < 4; ++ct) {
      s16x8 bh = *(const s16x8*)&sB[cur][0][(ct * 64 + lane) * 8];
      s16x8 bl = *(const s16x8*)&sB[cur][1][(ct * 64 + lane) * 8];
      f32x4& a = (ct == 0 ? acc0 : ct == 1 ? acc1 : ct == 2 ? acc2 : acc3);
      a = __builtin_amdgcn_mfma_f32_16x16x32_bf16(ah, bh, a, 0, 0, 0);
      a = __builtin_amdgcn_mfma_f32_16x16x32_bf16(ah, bl, a, 0, 0, 0);
      a = __builtin_amdgcn_mfma_f32_16x16x32_bf16(al, bh, a, 0, 0, 0);
    }
    if (ks < 31) {                      // write prefetched step to other buf
      *(s16x8*)&sA[cur ^ 1][0][slot] = pah;
      *(s16x8*)&sA[cur ^ 1][1][slot] = pal;
      *(s16x8*)&sB[cur ^ 1][0][slot] = pbh;
      *(s16x8*)&sB[cur ^ 1][1][slot] = pbl;
    }
    __syncthreads();
    cur ^= 1;
  }

  // epilogue: token-major store v_t[(b*1024 + token)*72 + c]
#pragma unroll
  for (int ct = 0; ct < 4; ++ct) {
    f32x4 a = (ct == 0 ? acc0 : ct == 1 ? acc1 : ct == 2 ? acc2 : acc3);
    int colg = col0 + ct * 16 + (lane & 15);
    float bias = bv[colg];
#pragma unroll
    for (int i = 0; i < 4; ++i) {
      int rowg = row0 + wv * 16 + (lane >> 4) * 4 + i;   // = b*72 + c
      int bb = rowg / 72;
      int cc = rowg - bb * 72;
      v_t[(bb * NTOK + colg) * C1 + cc] = a[i] + bias;
    }
  }
}

// ---------------------------------------------------------------------------
// Kernel 3 (v3, unchanged): cosine-sim + online top-3 + softmax.
// ---------------------------------------------------------------------------
#define INS(TV, TI, d, di)                                              \
  {                                                                     \
    if ((d) > TV[0] || ((d) == TV[0] && (di) < TI[0])) {                \
      TV[2] = TV[1]; TI[2] = TI[1];                                     \
      TV[1] = TV[0]; TI[1] = TI[0];                                     \
      TV[0] = (d);   TI[0] = (di);                                      \
    } else if ((d) > TV[1] || ((d) == TV[1] && (di) < TI[1])) {         \
      TV[2] = TV[1]; TI[2] = TI[1];                                     \
      TV[1] = (d);   TI[1] = (di);                                      \
    } else if ((d) > TV[2] || ((d) == TV[2] && (di) < TI[2])) {         \
      TV[2] = (d);   TI[2] = (di);                                      \
    }                                                                   \
  }

__global__ __launch_bounds__(512, 4) void k3_topk(const float* __restrict__ tn,
                                                  int* __restrict__ idxo,
                                                  float* __restrict__ attno) {
  __shared__ float smem[C1 * 64 + C1 * 128];   // arow | btile, 55.3 KB
  float* arow  = smem;              // [C1][64]
  float* btile = smem + C1 * 64;    // [C1][128]

  int wg = blockIdx.x;              // 0..511
  int xcd = wg & 7;
  int q = wg >> 3;                  // 0..63
  int b  = xcd * 4 + (q >> 4);      // 4 batches per XCD
  int n0 = (q & 15) * 64;
  int tid = threadIdx.x;
  int tx = tid & 31;   // col group: cols tx*4..+3 (of 128)
  int ty = tid >> 5;   // row group: rows ty*4..+3 (of 64)

  for (int e4 = tid; e4 < C1 * 16; e4 += 512) {
    int c = e4 >> 4, qq = e4 & 15;
    *(float4*)&arow[c * 64 + qq * 4] =
        *(const float4*)&tn[(b * C1 + c) * NTOK + n0 + qq * 4];
  }

  float tv[4][3];
  int   ti[4][3];
#pragma unroll
  for (int ri = 0; ri < 4; ++ri) {
    tv[ri][0] = tv[ri][1] = tv[ri][2] = -INFINITY;
    ti[ri][0] = ti[ri][1] = ti[ri][2] = 0x7fffffff;
  }

#pragma unroll 1
  for (int tl2 = 0; tl2 < 8; ++tl2) {
    int m0 = tl2 * 128;
    __syncthreads();
    for (int e4 = tid; e4 < C1 * 32; e4 += 512) {
      int c = e4 >> 5, qq = e4 & 31;
      *(float4*)&btile[c * 128 + qq * 4] =
          *(const float4*)&tn[(b * C1 + c) * NTOK + m0 + qq * 4];
    }
    __syncthreads();

    float4 acc0 = {0,0,0,0}, acc1 = {0,0,0,0}, acc2 = {0,0,0,0}, acc3 = {0,0,0,0};
#pragma unroll 4
    for (int c = 0; c < C1; ++c) {
      float4 av  = *(const float4*)&arow[c * 64 + ty * 4];
      float4 bv4 = *(const float4*)&btile[c * 128 + tx * 4];
      acc0.x += av.x * bv4.x; acc0.y += av.x * bv4.y;
      acc0.z += av.x * bv4.z; acc0.w += av.x * bv4.w;
      acc1.x += av.y * bv4.x; acc1.y += av.y * bv4.y;
      acc1.z += av.y * bv4.z; acc1.w += av.y * bv4.w;
      acc2.x += av.z * bv4.x; acc2.y += av.z * bv4.y;
      acc2.z += av.z * bv4.z; acc2.w += av.z * bv4.w;
      acc3.x += av.w * bv4.x; acc3.y += av.w * bv4.y;
      acc3.z += av.w * bv4.z; acc3.w += av.w * bv4.w;
    }
    int cb = m0 + tx * 4;
    float mx;
    mx = fmaxf(fmaxf(acc0.x, acc0.y), fmaxf(acc0.z, acc0.w));
    if (mx > tv[0][2]) {
      INS(tv[0], ti[0], acc0.x, cb + 0); INS(tv[0], ti[0], acc0.y, cb + 1);
      INS(tv[0], ti[0], acc0.z, cb + 2); INS(tv[0], ti[0], acc0.w, cb + 3);
    }
    mx = fmaxf(fmaxf(acc1.x, acc1.y), fmaxf(acc1.z, acc1.w));
    if (mx > tv[1][2]) {
      INS(tv[1], ti[1], acc1.x, cb + 0); INS(tv[1], ti[1], acc1.y, cb + 1);
      INS(tv[1], ti[1], acc1.z, cb + 2); INS(tv[1], ti[1], acc1.w, cb + 3);
    }
    mx = fmaxf(fmaxf(acc2.x, acc2.y), fmaxf(acc2.z, acc2.w));
    if (mx > tv[2][2]) {
      INS(tv[2], ti[2], acc2.x, cb + 0); INS(tv[2], ti[2], acc2.y, cb + 1);
      INS(tv[2], ti[2], acc2.z, cb + 2); INS(tv[2], ti[2], acc2.w, cb + 3);
    }
    mx = fmaxf(fmaxf(acc3.x, acc3.y), fmaxf(acc3.z, acc3.w));
    if (mx > tv[3][2]) {
      INS(tv[3], ti[3], acc3.x, cb + 0); INS(tv[3], ti[3], acc3.y, cb + 1);
      INS(tv[3], ti[3], acc3.z, cb + 2); INS(tv[3], ti[3], acc3.w, cb + 3);
    }
  }

  __syncthreads();
  float* mv = smem;
  int*   mi = (int*)(smem + 6144);
#pragma unroll
  for (int ri = 0; ri < 4; ++ri) {
    int row = ty * 4 + ri;
#pragma unroll
    for (int j = 0; j < 3; ++j) {
      mv[(row * 32 + tx) * 3 + j] = tv[ri][j];
      mi[(row * 32 + tx) * 3 + j] = ti[ri][j];
    }
  }
  __syncthreads();
  if (tid < 64) {
    float fv[3] = {-INFINITY, -INFINITY, -INFINITY};
    int   fi[3] = {0x7fffffff, 0x7fffffff, 0x7fffffff};
    for (int g = 0; g < 32; ++g) {
#pragma unroll
      for (int j = 0; j < 3; ++j) {
        float d  = mv[(tid * 32 + g) * 3 + j];
        int   di = mi[(tid * 32 + g) * 3 + j];
        INS(fv, fi, d, di);
      }
    }
    float e1 = expf(fv[1] - fv[0]), e2 = expf(fv[2] - fv[0]);
    float inv = 1.0f / (1.0f + e1 + e2);
    int ob = (b * NTOK + n0 + tid) * 3;
    idxo[ob] = fi[0]; idxo[ob + 1] = fi[1]; idxo[ob + 2] = fi[2];
    attno[ob] = inv; attno[ob + 1] = e1 * inv; attno[ob + 2] = e2 * inv;
  }
}

// ---------------------------------------------------------------------------
// Kernel 4 (v2, unchanged): token-major gather + conv1d GEMM.
// ---------------------------------------------------------------------------
__global__ __launch_bounds__(256) void k4_conv1d(const float* __restrict__ v_t,
                                                 const int* __restrict__ idx,
                                                 const float* __restrict__ attn,
                                                 const float* __restrict__ conv_w,
                                                 const float* __restrict__ conv_b,
                                                 float* __restrict__ out1d) {
  __shared__ float prime[64][220];
  __shared__ int   sidx[64][3];
  __shared__ float satt[64][3];
  int wg = blockIdx.x;
  int xcd = wg & 7;
  int q = wg >> 3;
  int b  = xcd * 4 + (q >> 4);
  int n0 = (q & 15) * 64;
  int tid = threadIdx.x;
  if (tid < 192) {
    int tok = tid / 3, k = tid % 3;
    sidx[tok][k] = idx[(b * NTOK + n0 + tok) * 3 + k];
    satt[tok][k] = attn[(b * NTOK + n0 + tok) * 3 + k];
  }
  __syncthreads();
  for (int u = tid; u < 64 * 3 * 18; u += 256) {
    int tok = u / 54;
    int r   = u - tok * 54;
    int k   = r / 18;
    int c4  = r - k * 18;
    float4 val = *(const float4*)&v_t[(b * NTOK + sidx[tok][k]) * C1 + c4 * 4];
    float s = satt[tok][k];
    int base = (c4 * 4) * 3 + k;
    prime[tok][base]     = val.x * s;
    prime[tok][base + 3] = val.y * s;
    prime[tok][base + 6] = val.z * s;
    prime[tok][base + 9] = val.w * s;
  }
  __syncthreads();
  int tok = tid & 63;
  int obase = __builtin_amdgcn_readfirstlane((int)(tid >> 6)) * 18;
  float acc[18];
#pragma unroll
  for (int j = 0; j < 18; ++j) acc[j] = 0.f;
  for (int ck4 = 0; ck4 < 54; ++ck4) {
    float4 p4 = *(const float4*)&prime[tok][ck4 * 4];
#pragma unroll
    for (int j = 0; j < 18; ++j) {
      float4 w4 = *(const float4*)&conv_w[(obase + j) * 216 + ck4 * 4];
      acc[j] += p4.x * w4.x + p4.y * w4.y + p4.z * w4.z + p4.w * w4.w;
    }
  }
#pragma unroll
  for (int j = 0; j < 18; ++j) {
    int o = obase + j;
    out1d[(b * C1 + o) * NTOK + n0 + tok] = acc[j] + conv_b[o];
  }
}

// ---------------------------------------------------------------------------
// Kernel 5: pixel_shuffle + pointwise 1x1 conv. (unchanged)
// ---------------------------------------------------------------------------
__global__ __launch_bounds__(256) void k5_pw(const float* __restrict__ out1d,
                                             const float* __restrict__ pw_w,
                                             const float* __restrict__ pw_b,
                                             float* __restrict__ out) {
  int gid = blockIdx.x * 256 + threadIdx.x;   // 131072 threads
  int b = gid >> 12;
  int p = gid & 4095;
  int h = p >> 6, w = p & 63;
  int hh = h >> 1, ww = w >> 1;
  int c1base = ((h & 1) << 1) | (w & 1);
  int n = hh * 32 + ww;
  float xs[18];
#pragma unroll
  for (int c = 0; c < 18; ++c)
    xs[c] = out1d[(b * C1 + c * 4 + c1base) * NTOK + n];
#pragma unroll
  for (int o = 0; o < 16; ++o) {
    float a = pw_b[o];
#pragma unroll
    for (int c = 0; c < 18; ++c) a += xs[c] * pw_w[o * 18 + c];
    out[((b * 16 + o) << 12) + p] = a;
  }
}

// ---------------------------------------------------------------------------
extern "C" void kernel_launch(void* const* d_in, const int* in_sizes, int n_in,
                              void* d_out, int out_size, void* d_ws, size_t ws_size,
                              hipStream_t stream) {
  (void)in_sizes; (void)n_in; (void)out_size; (void)ws_size;
  const float* x      = (const float*)d_in[0];
  const float* Wv     = (const float*)d_in[1];
  const float* bv     = (const float*)d_in[2];
  const float* conv_w = (const float*)d_in[3];
  const float* conv_b = (const float*)d_in[4];
  const float* pw_w   = (const float*)d_in[5];
  const float* pw_b   = (const float*)d_in[6];
  float* out = (float*)d_out;

  // workspace layout (33.3 MB): out1d aliases th/tl (dead after k2)
  const size_t SZ_T = (size_t)BB * C1 * NTOK * sizeof(float);   // 9,437,184
  const size_t SZ_H = (size_t)BB * C1 * NTOK * sizeof(short);   // 4,718,592
  char* ws = (char*)d_ws;
  float* tn    = (float*)(ws);
  short* th    = (short*)(ws + SZ_T);
  short* tl    = (short*)(ws + SZ_T + SZ_H);
  float* out1d = (float*)(ws + SZ_T);              // alias th+tl region
  float* v_t   = (float*)(ws + 2 * SZ_T);          // token-major [B][N][72]
  int*   idx   = (int*)  (ws + 3 * SZ_T);
  float* attn  = (float*)(ws + 3 * SZ_T + 393216);
  short* wh    = (short*)(ws + 3 * SZ_T + 2 * 393216);
  short* wl    = (short*)(ws + 3 * SZ_T + 2 * 393216 + 2097152);

  k1_build<<<dim3((BB * NTOK) / 128), 128, 0, stream>>>(x, th, tl, tn);
  k0_wcvt <<<dim3(1024), 256, 0, stream>>>(Wv, wh, wl);
  k2_vproj<<<dim3(576), 256, 0, stream>>>(th, tl, wh, wl, bv, v_t);
  k3_topk <<<dim3(512), 512, 0, stream>>>(tn, idx, attn);
  k4_conv1d<<<dim3(512), 256, 0, stream>>>(v_t, idx, attn, conv_w, conv_b, out1d);
  k5_pw   <<<dim3((BB * 4096) / 256), 256, 0, stream>>>(out1d, pw_w, pw_b, out);
}

// Round 10
// 301.419 us; speedup vs baseline: 11.5129x; 1.0184x over previous
//
#include <hip/hip_runtime.h>
#include <math.h>

// Problem constants
#define BB   32
#define CIN  16
#define C1   72      // (16+2)*2*2
#define NTOK 1024    // 32*32
#define HH   64
#define WW2  64

typedef float f32x4 __attribute__((ext_vector_type(4)));
typedef short s16x8 __attribute__((ext_vector_type(8)));
typedef short s16x4 __attribute__((ext_vector_type(4)));

// bf16 helpers (bit-ops). RNE.
__device__ __forceinline__ unsigned short f2bf(float f) {
  unsigned int u = __float_as_uint(f);
  unsigned int r = (u + 0x7FFFu + ((u >> 16) & 1u)) >> 16;
  return (unsigned short)r;
}
__device__ __forceinline__ float bf2f(unsigned short s) {
  return __uint_as_float(((unsigned int)s) << 16);
}

// ---------------------------------------------------------------------------
// Kernel 0: Wv fp32 -> (wh, wl) bf16 split pair. (unchanged)
// ---------------------------------------------------------------------------
__global__ __launch_bounds__(256) void k0_wcvt(const float* __restrict__ Wv,
                                               short* __restrict__ wh,
                                               short* __restrict__ wl) {
  int i4 = (blockIdx.x * 256 + threadIdx.x) * 4;
  float4 v = *(const float4*)&Wv[i4];
  unsigned short h0 = f2bf(v.x), h1 = f2bf(v.y), h2 = f2bf(v.z), h3 = f2bf(v.w);
  s16x4 hv = { (short)h0, (short)h1, (short)h2, (short)h3 };
  s16x4 lv = { (short)f2bf(v.x - bf2f(h0)), (short)f2bf(v.y - bf2f(h1)),
               (short)f2bf(v.z - bf2f(h2)), (short)f2bf(v.w - bf2f(h3)) };
  *(s16x4*)&wh[i4] = hv;
  *(s16x4*)&wl[i4] = lv;
}

// ---------------------------------------------------------------------------
// Kernel 1 (v3): coord-concat + pixel_unshuffle. Emits:
//  - th/tl: unnormalized t, 2-level bf16 split, channel-major (k2's layout)
//  - ts0/1/2: NORMALIZED tn, 3-level bf16 split, MFMA-fragment-linear layout
//    TS[lev][b][ks(3)][ntile(64)][lane(64)][j(8)]; lane=(klocal>>3)*16+(n&15),
//    k padded 72->96 with zeros (ks=2, lane-groups 1..3).
// fp32 tn dropped (k3 is now MFMA-based).
// ---------------------------------------------------------------------------
__global__ __launch_bounds__(128) void k1_build(const float* __restrict__ x,
                                                short* __restrict__ th,
                                                short* __restrict__ tl,
                                                short* __restrict__ ts0,
                                                short* __restrict__ ts1,
                                                short* __restrict__ ts2) {
  int gid = blockIdx.x * 128 + threadIdx.x;   // 32768 threads
  int b = gid >> 10;
  int n = gid & 1023;
  int hh = n >> 5, ww = n & 31;
  float vals[C1];
  float ss = 0.f;
#pragma unroll
  for (int c1 = 0; c1 < C1; ++c1) {
    int c = c1 >> 2, sh = (c1 >> 1) & 1, sw = c1 & 1;
    int h = 2 * hh + sh, w = 2 * ww + sw;
    float val;
    if (c < CIN) {
      val = x[((b * CIN + c) * HH + h) * WW2 + w];
    } else {
      float r = fmaxf(sqrtf((float)(h * h + w * w)), 1e-12f);
      val = (c == CIN ? (float)h : (float)w) / r;
    }
    vals[c1] = val;
    ss += val * val;
  }
  float inv = 1.0f / fmaxf(sqrtf(ss), 1e-12f);
  // th/tl for k2 (unnormalized)
#pragma unroll
  for (int c1 = 0; c1 < C1; ++c1) {
    int o = (b * C1 + c1) * NTOK + n;
    unsigned short h = f2bf(vals[c1]);
    th[o] = (short)h;
    tl[o] = (short)f2bf(vals[c1] - bf2f(h));
  }
  // TS planes for k3 (normalized, 3-level, fragment-linear)
  int nt = n >> 4, nl = n & 15;
#pragma unroll
  for (int ks = 0; ks < 3; ++ks)
#pragma unroll
    for (int g = 0; g < 4; ++g) {
      s16x8 v0, v1, v2;
#pragma unroll
      for (int j = 0; j < 8; ++j) {
        int c = ks * 32 + g * 8 + j;
        float f = (c < C1) ? vals[c] * inv : 0.f;
        unsigned short h0 = f2bf(f);
        float r0 = f - bf2f(h0);
        unsigned short h1 = f2bf(r0);
        float r1 = r0 - bf2f(h1);
        unsigned short h2 = f2bf(r1);
        v0[j] = (short)h0; v1[j] = (short)h1; v2[j] = (short)h2;
      }
      int off = (((b * 3 + ks) * 64 + nt) * 64 + (g * 16 + nl)) * 8;
      *(s16x8*)(ts0 + off) = v0;
      *(s16x8*)(ts1 + off) = v1;
      *(s16x8*)(ts2 + off) = v2;
    }
}

// ---------------------------------------------------------------------------
// Kernel 2 (v5, unchanged): V = t @ Wv^T + bv via split-bf16 MFMA.
// ---------------------------------------------------------------------------
#define K2S 32
__global__ __launch_bounds__(256) void k2_vproj(const short* __restrict__ th,
                                                const short* __restrict__ tl,
                                                const short* __restrict__ wh,
                                                const short* __restrict__ wl,
                                                const float* __restrict__ bv,
                                                float* __restrict__ v_t) {
  __shared__ short sA[2][2][2048];
  __shared__ short sB[2][2][2048];
  int wg = blockIdx.x;
  int xcd = wg & 7;
  int q = wg >> 3;
  int row0 = (q >> 1) * 64;
  int col0 = (xcd * 2 + (q & 1)) * 64;
  int tid = threadIdx.x;
  int wv = tid >> 6, lane = tid & 63;

  int srow = tid >> 2, skc = tid & 3;
  int slot = (((srow >> 4) * 64) + (srow & 15) + 16 * skc) * 8;
  const short* gAh = th + (row0 + srow) * 1024 + skc * 8;
  const short* gAl = tl + (row0 + srow) * 1024 + skc * 8;
  const short* gBh = wh + (col0 + srow) * 1024 + skc * 8;
  const short* gBl = wl + (col0 + srow) * 1024 + skc * 8;

  s16x8 pah = *(const s16x8*)gAh;
  s16x8 pal = *(const s16x8*)gAl;
  s16x8 pbh = *(const s16x8*)gBh;
  s16x8 pbl = *(const s16x8*)gBl;
  *(s16x8*)&sA[0][0][slot] = pah;  *(s16x8*)&sA[0][1][slot] = pal;
  *(s16x8*)&sB[0][0][slot] = pbh;  *(s16x8*)&sB[0][1][slot] = pbl;

  f32x4 acc0 = {0,0,0,0}, acc1 = {0,0,0,0}, acc2 = {0,0,0,0}, acc3 = {0,0,0,0};
  __syncthreads();

  int cur = 0;
#pragma unroll 1
  for (int ks = 0; ks < 32; ++ks) {
    if (ks < 31) {
      pah = *(const s16x8*)(gAh + (ks + 1) * K2S);
      pal = *(const s16x8*)(gAl + (ks + 1) * K2S);
      pbh = *(const s16x8*)(gBh + (ks + 1) * K2S);
      pbl = *(const s16x8*)(gBl + (ks + 1) * K2S);
    }
    s16x8 ah = *(const s16x8*)&sA[cur][0][(wv * 64 + lane) * 8];
    s16x8 al = *(const s16x8*)&sA[cur][1][(wv * 64 + lane) * 8];
#pragma unroll
    for (int ct = 0; ct < 4; ++ct) {
      s16x8 bh = *(const s16x8*)&sB[cur][0][(ct * 64 + lane) * 8];
      s16x8 bl = *(const s16x8*)&sB[cur][1][(ct * 64 + lane) * 8];
      f32x4& a = (ct == 0 ? acc0 : ct == 1 ? acc1 : ct == 2 ? acc2 : acc3);
      a = __builtin_amdgcn_mfma_f32_16x16x32_bf16(ah, bh, a, 0, 0, 0);
      a = __builtin_amdgcn_mfma_f32_16x16x32_bf16(ah, bl, a, 0, 0, 0);
      a = __builtin_amdgcn_mfma_f32_16x16x32_bf16(al, bh, a, 0, 0, 0);
    }
    if (ks < 31) {
      *(s16x8*)&sA[cur ^ 1][0][slot] = pah;
      *(s16x8*)&sA[cur ^ 1][1][slot] = pal;
      *(s16x8*)&sB[cur ^ 1][0][slot] = pbh;
      *(s16x8*)&sB[cur ^ 1][1][slot] = pbl;
    }
    __syncthreads();
    cur ^= 1;
  }

#pragma unroll
  for (int ct = 0; ct < 4; ++ct) {
    f32x4 a = (ct == 0 ? acc0 : ct == 1 ? acc1 : ct == 2 ? acc2 : acc3);
    int colg = col0 + ct * 16 + (lane & 15);
    float bias = bv[colg];
#pragma unroll
    for (int i = 0; i < 4; ++i) {
      int rowg = row0 + wv * 16 + (lane >> 4) * 4 + i;
      int bb = rowg / 72;
      int cc = rowg - bb * 72;
      v_t[(bb * NTOK + colg) * C1 + cc] = a[i] + bias;
    }
  }
}

// ---------------------------------------------------------------------------
// Kernel 3 (v5, MFMA): cosine-sim + online top-3 + softmax.
// 3-level split (6 products: dropped terms ~1.5e-8 << fp32 sum-order noise).
// Swapped operands: D[m,n]=mfma(A=m-tile, B=n-tile) -> lane owns col n=lane&15,
// 4 m's/lane/tile (row=(lane>>4)*4+reg) -> per-lane top-3, ascending m order.
// Block = 4 waves = 128 n-rows (wave: 2 n-subtiles, B-frags hoisted 72 VGPR).
// A-frags: 64-m chunks staged in LDS (36KB, lane-linear 16B, conflict-free),
// 2-barrier v3-style staging. 256 blocks (1/CU), XCD swizzle 4 batches/XCD.
// ---------------------------------------------------------------------------
#define INS(TV, TI, d, di)                                              \
  {                                                                     \
    if ((d) > TV[0] || ((d) == TV[0] && (di) < TI[0])) {                \
      TV[2] = TV[1]; TI[2] = TI[1];                                     \
      TV[1] = TV[0]; TI[1] = TI[0];                                     \
      TV[0] = (d);   TI[0] = (di);                                      \
    } else if ((d) > TV[1] || ((d) == TV[1] && (di) < TI[1])) {         \
      TV[2] = TV[1]; TI[2] = TI[1];                                     \
      TV[1] = (d);   TI[1] = (di);                                      \
    } else if ((d) > TV[2] || ((d) == TV[2] && (di) < TI[2])) {         \
      TV[2] = (d);   TI[2] = (di);                                      \
    }                                                                   \
  }

__global__ __launch_bounds__(256) void k3_topk(const short* __restrict__ ts0,
                                               const short* __restrict__ ts1,
                                               const short* __restrict__ ts2,
                                               int* __restrict__ idxo,
                                               float* __restrict__ attno) {
  __shared__ short btile[18432];   // [ks(3)][lev(3)][mtl(4)][lane(64)][8] 36KB
  int wg = blockIdx.x;             // 0..255
  int xcd = wg & 7;
  int q = wg >> 3;                 // 0..31
  int b  = xcd * 4 + (q >> 3);     // 4 batches per XCD
  int nb = q & 7;                  // n-block of 128 rows
  int tid = threadIdx.x;
  int wv = tid >> 6, lane = tid & 63;

  // hoist this wave's B-fragments (2 n-subtiles x 3 ksteps x 3 levels)
  s16x8 Bf[2][3][3];
#pragma unroll
  for (int ns = 0; ns < 2; ++ns)
#pragma unroll
    for (int ks = 0; ks < 3; ++ks) {
      int nt = nb * 8 + wv * 2 + ns;
      int off = (((b * 3 + ks) * 64 + nt) * 64 + lane) * 8;
      Bf[ns][ks][0] = *(const s16x8*)(ts0 + off);
      Bf[ns][ks][1] = *(const s16x8*)(ts1 + off);
      Bf[ns][ks][2] = *(const s16x8*)(ts2 + off);
    }

  float tv0[3] = {-INFINITY, -INFINITY, -INFINITY};
  float tv1[3] = {-INFINITY, -INFINITY, -INFINITY};
  int   ti0[3] = {0x7fffffff, 0x7fffffff, 0x7fffffff};
  int   ti1[3] = {0x7fffffff, 0x7fffffff, 0x7fffffff};

#pragma unroll 1
  for (int ch = 0; ch < 16; ++ch) {
    int mt0 = ch * 4;              // global m-tile base
    __syncthreads();               // previous chunk consumed
#pragma unroll
    for (int lev = 0; lev < 3; ++lev) {
      const short* tsp = (lev == 0 ? ts0 : lev == 1 ? ts1 : ts2);
#pragma unroll
      for (int sub = 0; sub < 3; ++sub) {
        int r = tid + sub * 256;   // 0..767
        int ks = r >> 8, mtl = (r >> 6) & 3, ln = r & 63;
        int g = (((b * 3 + ks) * 64 + (mt0 + mtl)) * 64 + ln) * 8;
        *(s16x8*)&btile[(((ks * 3 + lev) * 4 + mtl) * 64 + ln) * 8] =
            *(const s16x8*)(tsp + g);
      }
    }
    __syncthreads();

#pragma unroll
    for (int mtl = 0; mtl < 4; ++mtl) {
      f32x4 acc0 = {0, 0, 0, 0}, acc1 = {0, 0, 0, 0};
#pragma unroll
      for (int ks = 0; ks < 3; ++ks) {
        s16x8 a0 = *(const s16x8*)&btile[(((ks * 3 + 0) * 4 + mtl) * 64 + lane) * 8];
        s16x8 a1 = *(const s16x8*)&btile[(((ks * 3 + 1) * 4 + mtl) * 64 + lane) * 8];
        s16x8 a2 = *(const s16x8*)&btile[(((ks * 3 + 2) * 4 + mtl) * 64 + lane) * 8];
        acc0 = __builtin_amdgcn_mfma_f32_16x16x32_bf16(a0, Bf[0][ks][0], acc0, 0, 0, 0);
        acc0 = __builtin_amdgcn_mfma_f32_16x16x32_bf16(a0, Bf[0][ks][1], acc0, 0, 0, 0);
        acc0 = __builtin_amdgcn_mfma_f32_16x16x32_bf16(a1, Bf[0][ks][0], acc0, 0, 0, 0);
        acc0 = __builtin_amdgcn_mfma_f32_16x16x32_bf16(a0, Bf[0][ks][2], acc0, 0, 0, 0);
        acc0 = __builtin_amdgcn_mfma_f32_16x16x32_bf16(a1, Bf[0][ks][1], acc0, 0, 0, 0);
        acc0 = __builtin_amdgcn_mfma_f32_16x16x32_bf16(a2, Bf[0][ks][0], acc0, 0, 0, 0);
        acc1 = __builtin_amdgcn_mfma_f32_16x16x32_bf16(a0, Bf[1][ks][0], acc1, 0, 0, 0);
        acc1 = __builtin_amdgcn_mfma_f32_16x16x32_bf16(a0, Bf[1][ks][1], acc1, 0, 0, 0);
        acc1 = __builtin_amdgcn_mfma_f32_16x16x32_bf16(a1, Bf[1][ks][0], acc1, 0, 0, 0);
        acc1 = __builtin_amdgcn_mfma_f32_16x16x32_bf16(a0, Bf[1][ks][2], acc1, 0, 0, 0);
        acc1 = __builtin_amdgcn_mfma_f32_16x16x32_bf16(a1, Bf[1][ks][1], acc1, 0, 0, 0);
        acc1 = __builtin_amdgcn_mfma_f32_16x16x32_bf16(a2, Bf[1][ks][0], acc1, 0, 0, 0);
      }
      int mb = ch * 64 + mtl * 16 + ((lane >> 4) << 2);
      float mx0 = fmaxf(fmaxf(acc0[0], acc0[1]), fmaxf(acc0[2], acc0[3]));
      if (mx0 > tv0[2]) {
        INS(tv0, ti0, acc0[0], mb + 0); INS(tv0, ti0, acc0[1], mb + 1);
        INS(tv0, ti0, acc0[2], mb + 2); INS(tv0, ti0, acc0[3], mb + 3);
      }
      float mx1 = fmaxf(fmaxf(acc1[0], acc1[1]), fmaxf(acc1[2], acc1[3]));
      if (mx1 > tv1[2]) {
        INS(tv1, ti1, acc1[0], mb + 0); INS(tv1, ti1, acc1[1], mb + 1);
        INS(tv1, ti1, acc1[2], mb + 2); INS(tv1, ti1, acc1[3], mb + 3);
      }
    }
  }

  // merge: per n-row, 4 lane-groups hold disjoint m-subsets. [128 n][4 g][3]
  __syncthreads();
  float* mv = (float*)btile;             // 1536 floats (6144 B)
  int*   mi = ((int*)btile) + 1536;      // 1536 ints  (6144 B); total 12 KB
  int g2 = lane >> 4;
  {
    int nl0 = wv * 32 + (lane & 15);
#pragma unroll
    for (int j = 0; j < 3; ++j) {
      mv[((nl0)      * 4 + g2) * 3 + j] = tv0[j];
      mi[((nl0)      * 4 + g2) * 3 + j] = ti0[j];
      mv[((nl0 + 16) * 4 + g2) * 3 + j] = tv1[j];
      mi[((nl0 + 16) * 4 + g2) * 3 + j] = ti1[j];
    }
  }
  __syncthreads();
  if (tid < 128) {
    float fv[3] = {-INFINITY, -INFINITY, -INFINITY};
    int   fi[3] = {0x7fffffff, 0x7fffffff, 0x7fffffff};
#pragma unroll
    for (int g = 0; g < 4; ++g)
#pragma unroll
      for (int j = 0; j < 3; ++j) {
        float d  = mv[(tid * 4 + g) * 3 + j];
        int   di = mi[(tid * 4 + g) * 3 + j];
        INS(fv, fi, d, di);
      }
    float e1 = expf(fv[1] - fv[0]), e2 = expf(fv[2] - fv[0]);
    float inv = 1.0f / (1.0f + e1 + e2);
    int nn = nb * 128 + tid;
    int ob = (b * NTOK + nn) * 3;
    idxo[ob] = fi[0]; idxo[ob + 1] = fi[1]; idxo[ob + 2] = fi[2];
    attno[ob] = inv; attno[ob + 1] = e1 * inv; attno[ob + 2] = e2 * inv;
  }
}

// ---------------------------------------------------------------------------
// Kernel 4 (v2, unchanged): token-major gather + conv1d GEMM.
// ---------------------------------------------------------------------------
__global__ __launch_bounds__(256) void k4_conv1d(const float* __restrict__ v_t,
                                                 const int* __restrict__ idx,
                                                 const float* __restrict__ attn,
                                                 const float* __restrict__ conv_w,
                                                 const float* __restrict__ conv_b,
                                                 float* __restrict__ out1d) {
  __shared__ float prime[64][220];
  __shared__ int   sidx[64][3];
  __shared__ float satt[64][3];
  int wg = blockIdx.x;
  int xcd = wg & 7;
  int q = wg >> 3;
  int b  = xcd * 4 + (q >> 4);
  int n0 = (q & 15) * 64;
  int tid = threadIdx.x;
  if (tid < 192) {
    int tok = tid / 3, k = tid % 3;
    sidx[tok][k] = idx[(b * NTOK + n0 + tok) * 3 + k];
    satt[tok][k] = attn[(b * NTOK + n0 + tok) * 3 + k];
  }
  __syncthreads();
  for (int u = tid; u < 64 * 3 * 18; u += 256) {
    int tok = u / 54;
    int r   = u - tok * 54;
    int k   = r / 18;
    int c4  = r - k * 18;
    float4 val = *(const float4*)&v_t[(b * NTOK + sidx[tok][k]) * C1 + c4 * 4];
    float s = satt[tok][k];
    int base = (c4 * 4) * 3 + k;
    prime[tok][base]     = val.x * s;
    prime[tok][base + 3] = val.y * s;
    prime[tok][base + 6] = val.z * s;
    prime[tok][base + 9] = val.w * s;
  }
  __syncthreads();
  int tok = tid & 63;
  int obase = __builtin_amdgcn_readfirstlane((int)(tid >> 6)) * 18;
  float acc[18];
#pragma unroll
  for (int j = 0; j < 18; ++j) acc[j] = 0.f;
  for (int ck4 = 0; ck4 < 54; ++ck4) {
    float4 p4 = *(const float4*)&prime[tok][ck4 * 4];
#pragma unroll
    for (int j = 0; j < 18; ++j) {
      float4 w4 = *(const float4*)&conv_w[(obase + j) * 216 + ck4 * 4];
      acc[j] += p4.x * w4.x + p4.y * w4.y + p4.z * w4.z + p4.w * w4.w;
    }
  }
#pragma unroll
  for (int j = 0; j < 18; ++j) {
    int o = obase + j;
    out1d[(b * C1 + o) * NTOK + n0 + tok] = acc[j] + conv_b[o];
  }
}

// ---------------------------------------------------------------------------
// Kernel 5: pixel_shuffle + pointwise 1x1 conv. (unchanged)
// ---------------------------------------------------------------------------
__global__ __launch_bounds__(256) void k5_pw(const float* __restrict__ out1d,
                                             const float* __restrict__ pw_w,
                                             const float* __restrict__ pw_b,
                                             float* __restrict__ out) {
  int gid = blockIdx.x * 256 + threadIdx.x;
  int b = gid >> 12;
  int p = gid & 4095;
  int h = p >> 6, w = p & 63;
  int hh = h >> 1, ww = w >> 1;
  int c1base = ((h & 1) << 1) | (w & 1);
  int n = hh * 32 + ww;
  float xs[18];
#pragma unroll
  for (int c = 0; c < 18; ++c)
    xs[c] = out1d[(b * C1 + c * 4 + c1base) * NTOK + n];
#pragma unroll
  for (int o = 0; o < 16; ++o) {
    float a = pw_b[o];
#pragma unroll
    for (int c = 0; c < 18; ++c) a += xs[c] * pw_w[o * 18 + c];
    out[((b * 16 + o) << 12) + p] = a;
  }
}

// ---------------------------------------------------------------------------
extern "C" void kernel_launch(void* const* d_in, const int* in_sizes, int n_in,
                              void* d_out, int out_size, void* d_ws, size_t ws_size,
                              hipStream_t stream) {
  (void)in_sizes; (void)n_in; (void)out_size; (void)ws_size;
  const float* x      = (const float*)d_in[0];
  const float* Wv     = (const float*)d_in[1];
  const float* bv     = (const float*)d_in[2];
  const float* conv_w = (const float*)d_in[3];
  const float* conv_b = (const float*)d_in[4];
  const float* pw_w   = (const float*)d_in[5];
  const float* pw_b   = (const float*)d_in[6];
  float* out = (float*)d_out;

  // workspace layout (40.0 MiB), lifetime-aliased:
  //  [0        ) th 4.72M | tl 4.72M   (k1->k2)   === out1d 9.44M (k4->k5)
  //  [9437184  ) wh 2.1M  | wl 2.1M    (k0->k2)   === idx/attn 0.79M (k3->k4)
  //  [13631488 ) ts0|ts1|ts2 3x6.29M   (k1->k3)
  //  [32505856 ) v_t 9.44M             (k2->k4)
  char* ws = (char*)d_ws;
  short* th    = (short*)(ws);
  short* tl    = (short*)(ws + 4718592);
  float* out1d = (float*)(ws);                       // alias th/tl
  short* wh    = (short*)(ws + 9437184);
  short* wl    = (short*)(ws + 11534336);
  int*   idx   = (int*)  (ws + 9437184);             // alias wh/wl
  float* attn  = (float*)(ws + 9830400);
  short* ts0   = (short*)(ws + 13631488);
  short* ts1   = (short*)(ws + 19922944);
  short* ts2   = (short*)(ws + 26214400);
  float* v_t   = (float*)(ws + 32505856);

  k1_build<<<dim3((BB * NTOK) / 128), 128, 0, stream>>>(x, th, tl, ts0, ts1, ts2);
  k0_wcvt <<<dim3(1024), 256, 0, stream>>>(Wv, wh, wl);
  k2_vproj<<<dim3(576), 256, 0, stream>>>(th, tl, wh, wl, bv, v_t);
  k3_topk <<<dim3(256), 256, 0, stream>>>(ts0, ts1, ts2, idx, attn);
  k4_conv1d<<<dim3(512), 256, 0, stream>>>(v_t, idx, attn, conv_w, conv_b, out1d);
  k5_pw   <<<dim3((BB * 4096) / 256), 256, 0, stream>>>(out1d, pw_w, pw_b, out);
}

// Round 11
// 258.528 us; speedup vs baseline: 13.4229x; 1.1659x over previous
//
#include <hip/hip_runtime.h>
#include <math.h>

// Problem constants
#define BB   32
#define CIN  16
#define C1   72      // (16+2)*2*2
#define NTOK 1024    // 32*32
#define HH   64
#define WW2  64

typedef float f32x4 __attribute__((ext_vector_type(4)));
typedef short s16x8 __attribute__((ext_vector_type(8)));
typedef short s16x4 __attribute__((ext_vector_type(4)));

// bf16 helpers (bit-ops). RNE.
__device__ __forceinline__ unsigned short f2bf(float f) {
  unsigned int u = __float_as_uint(f);
  unsigned int r = (u + 0x7FFFu + ((u >> 16) & 1u)) >> 16;
  return (unsigned short)r;
}
__device__ __forceinline__ float bf2f(unsigned short s) {
  return __uint_as_float(((unsigned int)s) << 16);
}

// ---------------------------------------------------------------------------
// Kernel 0: Wv fp32 -> (wh, wl) bf16 split pair. (unchanged)
// ---------------------------------------------------------------------------
__global__ __launch_bounds__(256) void k0_wcvt(const float* __restrict__ Wv,
                                               short* __restrict__ wh,
                                               short* __restrict__ wl) {
  int i4 = (blockIdx.x * 256 + threadIdx.x) * 4;
  float4 v = *(const float4*)&Wv[i4];
  unsigned short h0 = f2bf(v.x), h1 = f2bf(v.y), h2 = f2bf(v.z), h3 = f2bf(v.w);
  s16x4 hv = { (short)h0, (short)h1, (short)h2, (short)h3 };
  s16x4 lv = { (short)f2bf(v.x - bf2f(h0)), (short)f2bf(v.y - bf2f(h1)),
               (short)f2bf(v.z - bf2f(h2)), (short)f2bf(v.w - bf2f(h3)) };
  *(s16x4*)&wh[i4] = hv;
  *(s16x4*)&wl[i4] = lv;
}

// ---------------------------------------------------------------------------
// Kernel 1 (v3, unchanged): coord-concat + pixel_unshuffle -> th/tl (k2) and
// ts0/1/2 (k3, normalized 3-level split, fragment-linear).
// ---------------------------------------------------------------------------
__global__ __launch_bounds__(128) void k1_build(const float* __restrict__ x,
                                                short* __restrict__ th,
                                                short* __restrict__ tl,
                                                short* __restrict__ ts0,
                                                short* __restrict__ ts1,
                                                short* __restrict__ ts2) {
  int gid = blockIdx.x * 128 + threadIdx.x;   // 32768 threads
  int b = gid >> 10;
  int n = gid & 1023;
  int hh = n >> 5, ww = n & 31;
  float vals[C1];
  float ss = 0.f;
#pragma unroll
  for (int c1 = 0; c1 < C1; ++c1) {
    int c = c1 >> 2, sh = (c1 >> 1) & 1, sw = c1 & 1;
    int h = 2 * hh + sh, w = 2 * ww + sw;
    float val;
    if (c < CIN) {
      val = x[((b * CIN + c) * HH + h) * WW2 + w];
    } else {
      float r = fmaxf(sqrtf((float)(h * h + w * w)), 1e-12f);
      val = (c == CIN ? (float)h : (float)w) / r;
    }
    vals[c1] = val;
    ss += val * val;
  }
  float inv = 1.0f / fmaxf(sqrtf(ss), 1e-12f);
#pragma unroll
  for (int c1 = 0; c1 < C1; ++c1) {
    int o = (b * C1 + c1) * NTOK + n;
    unsigned short h = f2bf(vals[c1]);
    th[o] = (short)h;
    tl[o] = (short)f2bf(vals[c1] - bf2f(h));
  }
  int nt = n >> 4, nl = n & 15;
#pragma unroll
  for (int ks = 0; ks < 3; ++ks)
#pragma unroll
    for (int g = 0; g < 4; ++g) {
      s16x8 v0, v1, v2;
#pragma unroll
      for (int j = 0; j < 8; ++j) {
        int c = ks * 32 + g * 8 + j;
        float f = (c < C1) ? vals[c] * inv : 0.f;
        unsigned short h0 = f2bf(f);
        float r0 = f - bf2f(h0);
        unsigned short h1 = f2bf(r0);
        float r1 = r0 - bf2f(h1);
        unsigned short h2 = f2bf(r1);
        v0[j] = (short)h0; v1[j] = (short)h1; v2[j] = (short)h2;
      }
      int off = (((b * 3 + ks) * 64 + nt) * 64 + (g * 16 + nl)) * 8;
      *(s16x8*)(ts0 + off) = v0;
      *(s16x8*)(ts1 + off) = v1;
      *(s16x8*)(ts2 + off) = v2;
    }
}

// ---------------------------------------------------------------------------
// Kernel 2 (v5, unchanged): V = t @ Wv^T + bv via split-bf16 MFMA.
// ---------------------------------------------------------------------------
#define K2S 32
__global__ __launch_bounds__(256) void k2_vproj(const short* __restrict__ th,
                                                const short* __restrict__ tl,
                                                const short* __restrict__ wh,
                                                const short* __restrict__ wl,
                                                const float* __restrict__ bv,
                                                float* __restrict__ v_t) {
  __shared__ short sA[2][2][2048];
  __shared__ short sB[2][2][2048];
  int wg = blockIdx.x;
  int xcd = wg & 7;
  int q = wg >> 3;
  int row0 = (q >> 1) * 64;
  int col0 = (xcd * 2 + (q & 1)) * 64;
  int tid = threadIdx.x;
  int wv = tid >> 6, lane = tid & 63;

  int srow = tid >> 2, skc = tid & 3;
  int slot = (((srow >> 4) * 64) + (srow & 15) + 16 * skc) * 8;
  const short* gAh = th + (row0 + srow) * 1024 + skc * 8;
  const short* gAl = tl + (row0 + srow) * 1024 + skc * 8;
  const short* gBh = wh + (col0 + srow) * 1024 + skc * 8;
  const short* gBl = wl + (col0 + srow) * 1024 + skc * 8;

  s16x8 pah = *(const s16x8*)gAh;
  s16x8 pal = *(const s16x8*)gAl;
  s16x8 pbh = *(const s16x8*)gBh;
  s16x8 pbl = *(const s16x8*)gBl;
  *(s16x8*)&sA[0][0][slot] = pah;  *(s16x8*)&sA[0][1][slot] = pal;
  *(s16x8*)&sB[0][0][slot] = pbh;  *(s16x8*)&sB[0][1][slot] = pbl;

  f32x4 acc0 = {0,0,0,0}, acc1 = {0,0,0,0}, acc2 = {0,0,0,0}, acc3 = {0,0,0,0};
  __syncthreads();

  int cur = 0;
#pragma unroll 1
  for (int ks = 0; ks < 32; ++ks) {
    if (ks < 31) {
      pah = *(const s16x8*)(gAh + (ks + 1) * K2S);
      pal = *(const s16x8*)(gAl + (ks + 1) * K2S);
      pbh = *(const s16x8*)(gBh + (ks + 1) * K2S);
      pbl = *(const s16x8*)(gBl + (ks + 1) * K2S);
    }
    s16x8 ah = *(const s16x8*)&sA[cur][0][(wv * 64 + lane) * 8];
    s16x8 al = *(const s16x8*)&sA[cur][1][(wv * 64 + lane) * 8];
#pragma unroll
    for (int ct = 0; ct < 4; ++ct) {
      s16x8 bh = *(const s16x8*)&sB[cur][0][(ct * 64 + lane) * 8];
      s16x8 bl = *(const s16x8*)&sB[cur][1][(ct * 64 + lane) * 8];
      f32x4& a = (ct == 0 ? acc0 : ct == 1 ? acc1 : ct == 2 ? acc2 : acc3);
      a = __builtin_amdgcn_mfma_f32_16x16x32_bf16(ah, bh, a, 0, 0, 0);
      a = __builtin_amdgcn_mfma_f32_16x16x32_bf16(ah, bl, a, 0, 0, 0);
      a = __builtin_amdgcn_mfma_f32_16x16x32_bf16(al, bh, a, 0, 0, 0);
    }
    if (ks < 31) {
      *(s16x8*)&sA[cur ^ 1][0][slot] = pah;
      *(s16x8*)&sA[cur ^ 1][1][slot] = pal;
      *(s16x8*)&sB[cur ^ 1][0][slot] = pbh;
      *(s16x8*)&sB[cur ^ 1][1][slot] = pbl;
    }
    __syncthreads();
    cur ^= 1;
  }

#pragma unroll
  for (int ct = 0; ct < 4; ++ct) {
    f32x4 a = (ct == 0 ? acc0 : ct == 1 ? acc1 : ct == 2 ? acc2 : acc3);
    int colg = col0 + ct * 16 + (lane & 15);
    float bias = bv[colg];
#pragma unroll
    for (int i = 0; i < 4; ++i) {
      int rowg = row0 + wv * 16 + (lane >> 4) * 4 + i;
      int bb = rowg / 72;
      int cc = rowg - bb * 72;
      v_t[(bb * NTOK + colg) * C1 + cc] = a[i] + bias;
    }
  }
}

// ---------------------------------------------------------------------------
// Kernel 3 (v6): MFMA cosine-sim + online top-3, M-SPLIT x4 for occupancy.
// v5 was latency-bound at 1 wave/SIMD (Occupancy 10.9%, MfmaUtil 12.6%).
// Grid 1024 = 8 xcd x (4 b x 8 nb x 4 mh): each block scans 4 chunks (256 m)
// -> 4 blocks/CU (LDS 4x36KB=144<=160KB), 4 waves/SIMD, 8 indep MFMA chains.
// Writes PARTIAL sorted top-3 (val,idx) per (row, mh); comparator is a strict
// total order so partial+merge is bit-exact vs monolithic scan.
// Inner loop/datapath identical to the verified v5.
// ---------------------------------------------------------------------------
#define INS(TV, TI, d, di)                                              \
  {                                                                     \
    if ((d) > TV[0] || ((d) == TV[0] && (di) < TI[0])) {                \
      TV[2] = TV[1]; TI[2] = TI[1];                                     \
      TV[1] = TV[0]; TI[1] = TI[0];                                     \
      TV[0] = (d);   TI[0] = (di);                                      \
    } else if ((d) > TV[1] || ((d) == TV[1] && (di) < TI[1])) {         \
      TV[2] = TV[1]; TI[2] = TI[1];                                     \
      TV[1] = (d);   TI[1] = (di);                                      \
    } else if ((d) > TV[2] || ((d) == TV[2] && (di) < TI[2])) {         \
      TV[2] = (d);   TI[2] = (di);                                      \
    }                                                                   \
  }

__global__ __launch_bounds__(256) void k3_topk(const short* __restrict__ ts0,
                                               const short* __restrict__ ts1,
                                               const short* __restrict__ ts2,
                                               float* __restrict__ pv,
                                               int* __restrict__ pi) {
  __shared__ short btile[18432];   // [ks(3)][lev(3)][mtl(4)][lane(64)][8] 36KB
  int wg = blockIdx.x;             // 0..1023
  int xcd = wg & 7;
  int q = wg >> 3;                 // 0..127
  int b  = xcd * 4 + (q >> 5);     // 4 batches per XCD
  int rem = q & 31;
  int nb = rem >> 2;               // n-block of 128 rows
  int mh = rem & 3;                // m-quarter (4 chunks = 256 m)
  int tid = threadIdx.x;
  int wv = tid >> 6, lane = tid & 63;

  // hoist this wave's B-fragments (2 n-subtiles x 3 ksteps x 3 levels)
  s16x8 Bf[2][3][3];
#pragma unroll
  for (int ns = 0; ns < 2; ++ns)
#pragma unroll
    for (int ks = 0; ks < 3; ++ks) {
      int nt = nb * 8 + wv * 2 + ns;
      int off = (((b * 3 + ks) * 64 + nt) * 64 + lane) * 8;
      Bf[ns][ks][0] = *(const s16x8*)(ts0 + off);
      Bf[ns][ks][1] = *(const s16x8*)(ts1 + off);
      Bf[ns][ks][2] = *(const s16x8*)(ts2 + off);
    }

  float tv0[3] = {-INFINITY, -INFINITY, -INFINITY};
  float tv1[3] = {-INFINITY, -INFINITY, -INFINITY};
  int   ti0[3] = {0x7fffffff, 0x7fffffff, 0x7fffffff};
  int   ti1[3] = {0x7fffffff, 0x7fffffff, 0x7fffffff};

#pragma unroll 1
  for (int ch = mh * 4; ch < mh * 4 + 4; ++ch) {
    int mt0 = ch * 4;              // global m-tile base
    __syncthreads();               // previous chunk consumed
#pragma unroll
    for (int lev = 0; lev < 3; ++lev) {
      const short* tsp = (lev == 0 ? ts0 : lev == 1 ? ts1 : ts2);
#pragma unroll
      for (int sub = 0; sub < 3; ++sub) {
        int r = tid + sub * 256;   // 0..767
        int ks = r >> 8, mtl = (r >> 6) & 3, ln = r & 63;
        int g = (((b * 3 + ks) * 64 + (mt0 + mtl)) * 64 + ln) * 8;
        *(s16x8*)&btile[(((ks * 3 + lev) * 4 + mtl) * 64 + ln) * 8] =
            *(const s16x8*)(tsp + g);
      }
    }
    __syncthreads();

#pragma unroll
    for (int mtl = 0; mtl < 4; ++mtl) {
      f32x4 acc0 = {0, 0, 0, 0}, acc1 = {0, 0, 0, 0};
#pragma unroll
      for (int ks = 0; ks < 3; ++ks) {
        s16x8 a0 = *(const s16x8*)&btile[(((ks * 3 + 0) * 4 + mtl) * 64 + lane) * 8];
        s16x8 a1 = *(const s16x8*)&btile[(((ks * 3 + 1) * 4 + mtl) * 64 + lane) * 8];
        s16x8 a2 = *(const s16x8*)&btile[(((ks * 3 + 2) * 4 + mtl) * 64 + lane) * 8];
        acc0 = __builtin_amdgcn_mfma_f32_16x16x32_bf16(a0, Bf[0][ks][0], acc0, 0, 0, 0);
        acc0 = __builtin_amdgcn_mfma_f32_16x16x32_bf16(a0, Bf[0][ks][1], acc0, 0, 0, 0);
        acc0 = __builtin_amdgcn_mfma_f32_16x16x32_bf16(a1, Bf[0][ks][0], acc0, 0, 0, 0);
        acc0 = __builtin_amdgcn_mfma_f32_16x16x32_bf16(a0, Bf[0][ks][2], acc0, 0, 0, 0);
        acc0 = __builtin_amdgcn_mfma_f32_16x16x32_bf16(a1, Bf[0][ks][1], acc0, 0, 0, 0);
        acc0 = __builtin_amdgcn_mfma_f32_16x16x32_bf16(a2, Bf[0][ks][0], acc0, 0, 0, 0);
        acc1 = __builtin_amdgcn_mfma_f32_16x16x32_bf16(a0, Bf[1][ks][0], acc1, 0, 0, 0);
        acc1 = __builtin_amdgcn_mfma_f32_16x16x32_bf16(a0, Bf[1][ks][1], acc1, 0, 0, 0);
        acc1 = __builtin_amdgcn_mfma_f32_16x16x32_bf16(a1, Bf[1][ks][0], acc1, 0, 0, 0);
        acc1 = __builtin_amdgcn_mfma_f32_16x16x32_bf16(a0, Bf[1][ks][2], acc1, 0, 0, 0);
        acc1 = __builtin_amdgcn_mfma_f32_16x16x32_bf16(a1, Bf[1][ks][1], acc1, 0, 0, 0);
        acc1 = __builtin_amdgcn_mfma_f32_16x16x32_bf16(a2, Bf[1][ks][0], acc1, 0, 0, 0);
      }
      int mb = ch * 64 + mtl * 16 + ((lane >> 4) << 2);
      float mx0 = fmaxf(fmaxf(acc0[0], acc0[1]), fmaxf(acc0[2], acc0[3]));
      if (mx0 > tv0[2]) {
        INS(tv0, ti0, acc0[0], mb + 0); INS(tv0, ti0, acc0[1], mb + 1);
        INS(tv0, ti0, acc0[2], mb + 2); INS(tv0, ti0, acc0[3], mb + 3);
      }
      float mx1 = fmaxf(fmaxf(acc1[0], acc1[1]), fmaxf(acc1[2], acc1[3]));
      if (mx1 > tv1[2]) {
        INS(tv1, ti1, acc1[0], mb + 0); INS(tv1, ti1, acc1[1], mb + 1);
        INS(tv1, ti1, acc1[2], mb + 2); INS(tv1, ti1, acc1[3], mb + 3);
      }
    }
  }

  // block merge: per n-row, 4 lane-groups hold disjoint m-subsets
  __syncthreads();
  float* mv = (float*)btile;
  int*   mi = ((int*)btile) + 1536;
  int g2 = lane >> 4;
  {
    int nl0 = wv * 32 + (lane & 15);
#pragma unroll
    for (int j = 0; j < 3; ++j) {
      mv[((nl0)      * 4 + g2) * 3 + j] = tv0[j];
      mi[((nl0)      * 4 + g2) * 3 + j] = ti0[j];
      mv[((nl0 + 16) * 4 + g2) * 3 + j] = tv1[j];
      mi[((nl0 + 16) * 4 + g2) * 3 + j] = ti1[j];
    }
  }
  __syncthreads();
  if (tid < 128) {
    float fv[3] = {-INFINITY, -INFINITY, -INFINITY};
    int   fi[3] = {0x7fffffff, 0x7fffffff, 0x7fffffff};
#pragma unroll
    for (int g = 0; g < 4; ++g)
#pragma unroll
      for (int j = 0; j < 3; ++j) {
        float d  = mv[(tid * 4 + g) * 3 + j];
        int   di = mi[(tid * 4 + g) * 3 + j];
        INS(fv, fi, d, di);
      }
    int nn = nb * 128 + tid;
    int ob = ((b * NTOK + nn) * 4 + mh) * 3;
#pragma unroll
    for (int j = 0; j < 3; ++j) { pv[ob + j] = fv[j]; pi[ob + j] = fi[j]; }
  }
}

// ---------------------------------------------------------------------------
// Kernel 3m: merge 4 partial top-3 lists per row -> final top-3 + softmax.
// Total order on (val desc, idx asc) makes this bit-exact.
// ---------------------------------------------------------------------------
__global__ __launch_bounds__(256) void k3m(const float* __restrict__ pv,
                                           const int* __restrict__ pi,
                                           int* __restrict__ idxo,
                                           float* __restrict__ attno) {
  int r = blockIdx.x * 256 + threadIdx.x;   // 0..32767 = b*1024+n
  float fv[3] = {-INFINITY, -INFINITY, -INFINITY};
  int   fi[3] = {0x7fffffff, 0x7fffffff, 0x7fffffff};
#pragma unroll
  for (int u = 0; u < 12; ++u) {
    float d  = pv[r * 12 + u];
    int   di = pi[r * 12 + u];
    INS(fv, fi, d, di);
  }
  float e1 = expf(fv[1] - fv[0]), e2 = expf(fv[2] - fv[0]);
  float inv = 1.0f / (1.0f + e1 + e2);
  int ob = r * 3;
  idxo[ob] = fi[0]; idxo[ob + 1] = fi[1]; idxo[ob + 2] = fi[2];
  attno[ob] = inv; attno[ob + 1] = e1 * inv; attno[ob + 2] = e2 * inv;
}

// ---------------------------------------------------------------------------
// Kernel 4 (v2, unchanged): token-major gather + conv1d GEMM.
// ---------------------------------------------------------------------------
__global__ __launch_bounds__(256) void k4_conv1d(const float* __restrict__ v_t,
                                                 const int* __restrict__ idx,
                                                 const float* __restrict__ attn,
                                                 const float* __restrict__ conv_w,
                                                 const float* __restrict__ conv_b,
                                                 float* __restrict__ out1d) {
  __shared__ float prime[64][220];
  __shared__ int   sidx[64][3];
  __shared__ float satt[64][3];
  int wg = blockIdx.x;
  int xcd = wg & 7;
  int q = wg >> 3;
  int b  = xcd * 4 + (q >> 4);
  int n0 = (q & 15) * 64;
  int tid = threadIdx.x;
  if (tid < 192) {
    int tok = tid / 3, k = tid % 3;
    sidx[tok][k] = idx[(b * NTOK + n0 + tok) * 3 + k];
    satt[tok][k] = attn[(b * NTOK + n0 + tok) * 3 + k];
  }
  __syncthreads();
  for (int u = tid; u < 64 * 3 * 18; u += 256) {
    int tok = u / 54;
    int r   = u - tok * 54;
    int k   = r / 18;
    int c4  = r - k * 18;
    float4 val = *(const float4*)&v_t[(b * NTOK + sidx[tok][k]) * C1 + c4 * 4];
    float s = satt[tok][k];
    int base = (c4 * 4) * 3 + k;
    prime[tok][base]     = val.x * s;
    prime[tok][base + 3] = val.y * s;
    prime[tok][base + 6] = val.z * s;
    prime[tok][base + 9] = val.w * s;
  }
  __syncthreads();
  int tok = tid & 63;
  int obase = __builtin_amdgcn_readfirstlane((int)(tid >> 6)) * 18;
  float acc[18];
#pragma unroll
  for (int j = 0; j < 18; ++j) acc[j] = 0.f;
  for (int ck4 = 0; ck4 < 54; ++ck4) {
    float4 p4 = *(const float4*)&prime[tok][ck4 * 4];
#pragma unroll
    for (int j = 0; j < 18; ++j) {
      float4 w4 = *(const float4*)&conv_w[(obase + j) * 216 + ck4 * 4];
      acc[j] += p4.x * w4.x + p4.y * w4.y + p4.z * w4.z + p4.w * w4.w;
    }
  }
#pragma unroll
  for (int j = 0; j < 18; ++j) {
    int o = obase + j;
    out1d[(b * C1 + o) * NTOK + n0 + tok] = acc[j] + conv_b[o];
  }
}

// ---------------------------------------------------------------------------
// Kernel 5: pixel_shuffle + pointwise 1x1 conv. (unchanged)
// ---------------------------------------------------------------------------
__global__ __launch_bounds__(256) void k5_pw(const float* __restrict__ out1d,
                                             const float* __restrict__ pw_w,
                                             const float* __restrict__ pw_b,
                                             float* __restrict__ out) {
  int gid = blockIdx.x * 256 + threadIdx.x;
  int b = gid >> 12;
  int p = gid & 4095;
  int h = p >> 6, w = p & 63;
  int hh = h >> 1, ww = w >> 1;
  int c1base = ((h & 1) << 1) | (w & 1);
  int n = hh * 32 + ww;
  float xs[18];
#pragma unroll
  for (int c = 0; c < 18; ++c)
    xs[c] = out1d[(b * C1 + c * 4 + c1base) * NTOK + n];
#pragma unroll
  for (int o = 0; o < 16; ++o) {
    float a = pw_b[o];
#pragma unroll
    for (int c = 0; c < 18; ++c) a += xs[c] * pw_w[o * 18 + c];
    out[((b * 16 + o) << 12) + p] = a;
  }
}

// ---------------------------------------------------------------------------
extern "C" void kernel_launch(void* const* d_in, const int* in_sizes, int n_in,
                              void* d_out, int out_size, void* d_ws, size_t ws_size,
                              hipStream_t stream) {
  (void)in_sizes; (void)n_in; (void)out_size; (void)ws_size;
  const float* x      = (const float*)d_in[0];
  const float* Wv     = (const float*)d_in[1];
  const float* bv     = (const float*)d_in[2];
  const float* conv_w = (const float*)d_in[3];
  const float* conv_b = (const float*)d_in[4];
  const float* pw_w   = (const float*)d_in[5];
  const float* pw_b   = (const float*)d_in[6];
  float* out = (float*)d_out;

  // workspace layout (40.0 MiB), lifetime-aliased:
  //  [0        ) th|tl 9.44M (k1->k2) === pv|pi 3.1M (k3->k3m) === out1d (k4->k5)
  //  [9437184  ) wh|wl 4.2M  (k0->k2) === idx/attn 0.79M (k3m->k4)
  //  [13631488 ) ts0|ts1|ts2 3x6.29M  (k1->k3)
  //  [32505856 ) v_t 9.44M            (k2->k4)
  char* ws = (char*)d_ws;
  short* th    = (short*)(ws);
  short* tl    = (short*)(ws + 4718592);
  float* pv    = (float*)(ws);                       // alias th (dead post-k2)
  int*   pi    = (int*)  (ws + 2097152);
  float* out1d = (float*)(ws);                       // alias pv/pi (post-k3m)
  short* wh    = (short*)(ws + 9437184);
  short* wl    = (short*)(ws + 11534336);
  int*   idx   = (int*)  (ws + 9437184);             // alias wh/wl (post-k2)
  float* attn  = (float*)(ws + 9830400);
  short* ts0   = (short*)(ws + 13631488);
  short* ts1   = (short*)(ws + 19922944);
  short* ts2   = (short*)(ws + 26214400);
  float* v_t   = (float*)(ws + 32505856);

  k1_build<<<dim3((BB * NTOK) / 128), 128, 0, stream>>>(x, th, tl, ts0, ts1, ts2);
  k0_wcvt <<<dim3(1024), 256, 0, stream>>>(Wv, wh, wl);
  k2_vproj<<<dim3(576), 256, 0, stream>>>(th, tl, wh, wl, bv, v_t);
  k3_topk <<<dim3(1024), 256, 0, stream>>>(ts0, ts1, ts2, pv, pi);
  k3m     <<<dim3(128), 256, 0, stream>>>(pv, pi, idx, attn);
  k4_conv1d<<<dim3(512), 256, 0, stream>>>(v_t, idx, attn, conv_w, conv_b, out1d);
  k5_pw   <<<dim3((BB * 4096) / 256), 256, 0, stream>>>(out1d, pw_w, pw_b, out);
}